// Round 3
// baseline (347.161 us; speedup 1.0000x reference)
//
#include <hip/hip_runtime.h>
#include <hip/hip_cooperative_groups.h>

namespace cg = cooperative_groups;

#define DFEAT 128
#define HID 16
#define BKT_NODES 128      // dst nodes per bucket -> nbkt=782
#define BKT_SHIFT 7
#define CAP 2432           // mean 2048 + ~8.5 sigma
#define CAPI 10            // ceil(CAP/256) register-cache iterations
#define CHUNK 4096         // edges per partition block -> 391 blocks
#define NOEDGE 0xFFFFFFFFu

typedef __attribute__((ext_vector_type(8))) short short8;
typedef __attribute__((ext_vector_type(4))) float floatx4;

__device__ __forceinline__ float bf2f(unsigned v) { return __uint_as_float(v << 16); }
__device__ __forceinline__ unsigned short f2bf(float f) {
    unsigned u = __float_as_uint(f);
    return (unsigned short)((u + 0x7FFFu + ((u >> 16) & 1u)) >> 16);
}
__device__ __forceinline__ unsigned pack2(float a, float b) {
    return (unsigned)f2bf(a) | ((unsigned)f2bf(b) << 16);
}
// Agent-scope (device-coherent) 32-bit load/store: cross-XCD L2s are NOT
// coherent; plain stores in one block are invisible to another block's plain
// loads within a single (cooperative) kernel. These hit the coherence point.
__device__ __forceinline__ unsigned ald(const unsigned* p) {
    return __hip_atomic_load(p, __ATOMIC_RELAXED, __HIP_MEMORY_SCOPE_AGENT);
}
__device__ __forceinline__ void ast(unsigned* p, unsigned v) {
    __hip_atomic_store(p, v, __ATOMIC_RELAXED, __HIP_MEMORY_SCOPE_AGENT);
}

// flags[0]=1 if float tensors are bf16; flags[1]=1 if edge_index is int64.
__global__ __launch_bounds__(512) void k_detect(const unsigned short* __restrict__ x,
                                                const int* __restrict__ ei,
                                                int* __restrict__ flags,
                                                int* __restrict__ gcur, int nbkt) {
    const int t = threadIdx.x;
    for (int i = t; i < nbkt; i += 512) gcur[i] = 0;
    if (t < 64) {
        unsigned short v = x[2 * t];
        int e = (v >> 7) & 0xFF;
        bool okbf = (v == 0) || (e >= 110 && e <= 130);
        unsigned long long mbf = __ballot(okbf);
        bool z = (ei[2 * t + 1] == 0);
        unsigned long long mz = __ballot(z);
        if (t == 0) {
            flags[0] = (__popcll(mbf) >= 52) ? 1 : 0;
            flags[1] = (__popcll(mz) >= 60) ? 1 : 0;
        }
    }
}

// FUSED: edge partition (blocks [0, nPart)) + layer-1 projection (rest).
__global__ __launch_bounds__(256) void k_pl(const int* __restrict__ ei,
                                            unsigned* __restrict__ eb,
                                            int* __restrict__ gcur,
                                            const void* __restrict__ xv,
                                            const void* __restrict__ wrel,
                                            const void* __restrict__ wroot,
                                            unsigned short* __restrict__ p1b,
                                            unsigned short* __restrict__ q1b,
                                            const int* __restrict__ flags,
                                            int E, int nbkt, int N, int nPart) {
    __shared__ int hist[1024];
    const int t = threadIdx.x;

    if ((int)blockIdx.x < nPart) {
        for (int i = t; i < nbkt; i += 256) hist[i] = 0;
        __syncthreads();
        const int base = blockIdx.x * CHUNK;
        const int i64 = flags[1];
        unsigned pk[16];
        unsigned short bk[16];
        if (i64 && !(E & 1)) {
#pragma unroll
            for (int ip = 0; ip < 8; ++ip) {
                int e = base + ip * 512 + 2 * t;
                if (e < E) {   // E even, e even -> e+1 < E too
                    int4 sv = *(const int4*)(ei + 2 * (size_t)e);
                    int4 dv = *(const int4*)(ei + 2 * ((size_t)E + e));
                    int b0 = dv.x >> BKT_SHIFT;
                    pk[2 * ip] = ((unsigned)sv.x << BKT_SHIFT) | (unsigned)(dv.x & (BKT_NODES - 1));
                    bk[2 * ip] = (unsigned short)b0;
                    atomicAdd(&hist[b0], 1);
                    int b1 = dv.z >> BKT_SHIFT;
                    pk[2 * ip + 1] = ((unsigned)sv.z << BKT_SHIFT) | (unsigned)(dv.z & (BKT_NODES - 1));
                    bk[2 * ip + 1] = (unsigned short)b1;
                    atomicAdd(&hist[b1], 1);
                } else {
                    bk[2 * ip] = 0xFFFFu;
                    bk[2 * ip + 1] = 0xFFFFu;
                }
            }
        } else {
#pragma unroll
            for (int i = 0; i < 16; ++i) {
                int e = base + i * 256 + t;
                if (e < E) {
                    int src, dst;
                    if (i64) { src = ei[2 * (size_t)e]; dst = ei[2 * ((size_t)E + e)]; }
                    else     { src = ei[e];             dst = ei[(size_t)E + e]; }
                    int b = dst >> BKT_SHIFT;
                    pk[i] = ((unsigned)src << BKT_SHIFT) | (unsigned)(dst & (BKT_NODES - 1));
                    bk[i] = (unsigned short)b;
                    atomicAdd(&hist[b], 1);
                } else {
                    bk[i] = 0xFFFFu;
                }
            }
        }
        __syncthreads();
        for (int b = t; b < nbkt; b += 256) {
            int c = hist[b];
            hist[b] = c ? atomicAdd(&gcur[b], c) : 0;
        }
        __syncthreads();
#pragma unroll
        for (int i = 0; i < 16; ++i) {
            if (bk[i] != 0xFFFFu) {
                int pos = atomicAdd(&hist[bk[i]], 1);
                if (pos >= 0 && pos < CAP)
                    eb[(size_t)bk[i] * CAP + pos] = pk[i];
            }
        }
        return;
    }

    // ---------------- layer-1 projection path ----------------
    const int lane = t & 63, wave = t >> 6;
    const int bf = flags[0];
    const int m = lane & 15;
    const int quad = lane >> 4;
    const int nodebase = ((int)blockIdx.x - nPart) * 64 + wave * 16;

    short8 Brel[4], Broot[4];
    if (bf) {
        const unsigned short* a = (const unsigned short*)wrel;
        const unsigned short* c = (const unsigned short*)wroot;
#pragma unroll
        for (int kb = 0; kb < 4; ++kb) {
            short8 br, bo;
#pragma unroll
            for (int j = 0; j < 8; ++j) {
                int k = kb * 32 + quad * 8 + j;
                br[j] = (short)a[k * HID + m];
                bo[j] = (short)c[k * HID + m];
            }
            Brel[kb] = br; Broot[kb] = bo;
        }
    } else {
        const float* a = (const float*)wrel;
        const float* c = (const float*)wroot;
#pragma unroll
        for (int kb = 0; kb < 4; ++kb) {
            short8 br, bo;
#pragma unroll
            for (int j = 0; j < 8; ++j) {
                int k = kb * 32 + quad * 8 + j;
                br[j] = (short)f2bf(a[k * HID + m]);
                bo[j] = (short)f2bf(c[k * HID + m]);
            }
            Brel[kb] = br; Broot[kb] = bo;
        }
    }

    int row = nodebase + m;
    if (row >= N) row = N - 1;

    floatx4 accP = {0.f, 0.f, 0.f, 0.f}, accQ = {0.f, 0.f, 0.f, 0.f};
    if (bf) {
        const unsigned short* xp = (const unsigned short*)xv;
        const unsigned short* rp = xp + (size_t)row * DFEAT + quad * 8;
#pragma unroll
        for (int kb = 0; kb < 4; ++kb) {
            short8 A = *(const short8*)(rp + kb * 32);
            accP = __builtin_amdgcn_mfma_f32_16x16x32_bf16(A, Brel[kb], accP, 0, 0, 0);
            accQ = __builtin_amdgcn_mfma_f32_16x16x32_bf16(A, Broot[kb], accQ, 0, 0, 0);
        }
    } else {
        const float* xp = (const float*)xv;
        const float* rp = xp + (size_t)row * DFEAT + quad * 8;
#pragma unroll
        for (int kb = 0; kb < 4; ++kb) {
            float4 v0 = *(const float4*)(rp + kb * 32);
            float4 v1 = *(const float4*)(rp + kb * 32 + 4);
            short8 A;
            A[0] = (short)f2bf(v0.x); A[1] = (short)f2bf(v0.y);
            A[2] = (short)f2bf(v0.z); A[3] = (short)f2bf(v0.w);
            A[4] = (short)f2bf(v1.x); A[5] = (short)f2bf(v1.y);
            A[6] = (short)f2bf(v1.z); A[7] = (short)f2bf(v1.w);
            accP = __builtin_amdgcn_mfma_f32_16x16x32_bf16(A, Brel[kb], accP, 0, 0, 0);
            accQ = __builtin_amdgcn_mfma_f32_16x16x32_bf16(A, Broot[kb], accQ, 0, 0, 0);
        }
    }

#pragma unroll
    for (int r = 0; r < 4; ++r) {
        int node = nodebase + quad * 4 + r;
        if (node < N) {
            p1b[(size_t)node * HID + m] = f2bf(accP[r]);
            q1b[(size_t)node * HID + m] = f2bf(accQ[r]);
        }
    }
}

// COOPERATIVE fused layers. Cross-block dataflow (p2b) goes through
// agent-scope atomics (device coherence point) — round-2 failure showed
// plain stores are invisible across non-coherent per-XCD L2s.
__global__ __launch_bounds__(256) void k_sagg(const unsigned* __restrict__ eb,
                                              const int* __restrict__ gcur,
                                              const unsigned short* __restrict__ p1b,
                                              const unsigned short* __restrict__ q1b,
                                              const void* __restrict__ b1,
                                              const void* __restrict__ w2rel,
                                              const void* __restrict__ w2root,
                                              unsigned short* __restrict__ p2b,
                                              unsigned short* __restrict__ q2b,
                                              const void* __restrict__ b2,
                                              void* __restrict__ out,
                                              const int* __restrict__ flags,
                                              int N) {
    __shared__ unsigned srt[CAP];       // persists across grid.sync
    __shared__ int cnts[BKT_NODES];
    __shared__ int offs[BKT_NODES];
    __shared__ float4 swp[HID][8];
    __shared__ float sb[HID];
    __shared__ float sb2[HID];
    const int t = threadIdx.x;
    const int b = blockIdx.x;
    const int bf = flags[0];

    if (t < 128) {
        int k = t >> 3, p = t & 7;
        float4 w;
        if (bf) {
            const unsigned short* a = (const unsigned short*)w2rel;
            const unsigned short* c = (const unsigned short*)w2root;
            w = make_float4(bf2f(a[k * 16 + 2 * p]), bf2f(a[k * 16 + 2 * p + 1]),
                            bf2f(c[k * 16 + 2 * p]), bf2f(c[k * 16 + 2 * p + 1]));
        } else {
            const float* a = (const float*)w2rel;
            const float* c = (const float*)w2root;
            w = make_float4(a[k * 16 + 2 * p], a[k * 16 + 2 * p + 1],
                            c[k * 16 + 2 * p], c[k * 16 + 2 * p + 1]);
        }
        swp[k][p] = w;
    }
    if (t < HID) {
        sb[t]  = bf ? bf2f(((const unsigned short*)b1)[t]) : ((const float*)b1)[t];
        sb2[t] = bf ? bf2f(((const unsigned short*)b2)[t]) : ((const float*)b2)[t];
    }
    if (t < BKT_NODES) cnts[t] = 0;
    __syncthreads();

    int cnt = gcur[b];
    if (cnt < 0) cnt = 0;
    if (cnt > CAP) cnt = CAP;
    const unsigned* ep = eb + (size_t)b * CAP;

    unsigned ev[CAPI];
    int rk[CAPI];
#pragma unroll
    for (int i = 0; i < CAPI; ++i) {
        int e = i * 256 + t;
        if (e < cnt) {
            unsigned w = ep[e];
            ev[i] = w;
            rk[i] = atomicAdd(&cnts[w & (BKT_NODES - 1u)], 1);
        } else ev[i] = NOEDGE;
    }
    __syncthreads();
    if (t < BKT_NODES) offs[t] = cnts[t];
    __syncthreads();
    for (int off = 1; off < BKT_NODES; off <<= 1) {
        int v = 0;
        if (t >= off && t < BKT_NODES) v = offs[t - off];
        __syncthreads();
        if (t < BKT_NODES) offs[t] += v;
        __syncthreads();
    }
#pragma unroll
    for (int i = 0; i < CAPI; ++i) {
        if (ev[i] != NOEDGE) {
            unsigned local = ev[i] & (BKT_NODES - 1u);
            int pos = offs[local] - cnts[local] + rk[i];
            srt[pos] = ev[i] >> BKT_SHIFT;
        }
    }
    __syncthreads();

    const int gb = b * BKT_NODES;
    const int grp = t >> 3, jp = t & 7;

    // ---- phase 1: layer-1 aggregate + relu/bias + layer-2 linear
#pragma unroll
    for (int g = 0; g < 4; ++g) {
        int node = g * 32 + grp;
        int gn = gb + node;
        int beg = offs[node] - cnts[node];
        int end = offs[node];
        float2 acc = make_float2(0.f, 0.f);
        int e = beg;
        for (; e + 4 <= end; e += 4) {
            unsigned s0 = srt[e], s1 = srt[e + 1], s2 = srt[e + 2], s3 = srt[e + 3];
            unsigned u0 = *(const unsigned*)(p1b + (size_t)s0 * HID + 2 * jp);
            unsigned u1 = *(const unsigned*)(p1b + (size_t)s1 * HID + 2 * jp);
            unsigned u2 = *(const unsigned*)(p1b + (size_t)s2 * HID + 2 * jp);
            unsigned u3 = *(const unsigned*)(p1b + (size_t)s3 * HID + 2 * jp);
            acc.x += bf2f(u0 & 0xFFFFu) + bf2f(u1 & 0xFFFFu)
                   + bf2f(u2 & 0xFFFFu) + bf2f(u3 & 0xFFFFu);
            acc.y += bf2f(u0 >> 16) + bf2f(u1 >> 16) + bf2f(u2 >> 16) + bf2f(u3 >> 16);
        }
        for (; e < end; ++e) {
            unsigned u = *(const unsigned*)(p1b + (size_t)srt[e] * HID + 2 * jp);
            acc.x += bf2f(u & 0xFFFFu);
            acc.y += bf2f(u >> 16);
        }
        float hx = 0.f, hy = 0.f;
        if (gn < N) {
            unsigned qu = *(const unsigned*)(q1b + (size_t)gn * HID + 2 * jp);
            hx = fmaxf(acc.x + bf2f(qu & 0xFFFFu) + sb[2 * jp], 0.f);
            hy = fmaxf(acc.y + bf2f(qu >> 16) + sb[2 * jp + 1], 0.f);
        }
        float2 sp = make_float2(0.f, 0.f), sq = make_float2(0.f, 0.f);
#pragma unroll
        for (int k = 0; k < HID; ++k) {
            float hsel = (k & 1) ? hy : hx;
            float hk = __shfl(hsel, k >> 1, 8);
            float4 w = swp[k][jp];
            sp.x += hk * w.x; sp.y += hk * w.y;
            sq.x += hk * w.z; sq.y += hk * w.w;
        }
        if (gn < N) {
            ast((unsigned*)p2b + (size_t)gn * 8 + jp, pack2(sp.x, sp.y));   // cross-block
            ((unsigned*)q2b)[(size_t)gn * 8 + jp] = pack2(sq.x, sq.y);      // own-block
        }
    }

    __threadfence();
    cg::this_grid().sync();

    // ---- phase 2: layer-2 aggregate (agent-scope p2b gathers) + log_softmax
#pragma unroll
    for (int g = 0; g < 4; ++g) {
        int node = g * 32 + grp;
        int gn = gb + node;
        int beg = offs[node] - cnts[node];
        int end = offs[node];
        float2 acc = make_float2(0.f, 0.f);
        const unsigned* pb = (const unsigned*)p2b;
        int e = beg;
        for (; e + 8 <= end; e += 8) {
            unsigned s0 = srt[e],     s1 = srt[e + 1], s2 = srt[e + 2], s3 = srt[e + 3];
            unsigned s4 = srt[e + 4], s5 = srt[e + 5], s6 = srt[e + 6], s7 = srt[e + 7];
            unsigned u0 = ald(pb + (size_t)s0 * 8 + jp);
            unsigned u1 = ald(pb + (size_t)s1 * 8 + jp);
            unsigned u2 = ald(pb + (size_t)s2 * 8 + jp);
            unsigned u3 = ald(pb + (size_t)s3 * 8 + jp);
            unsigned u4 = ald(pb + (size_t)s4 * 8 + jp);
            unsigned u5 = ald(pb + (size_t)s5 * 8 + jp);
            unsigned u6 = ald(pb + (size_t)s6 * 8 + jp);
            unsigned u7 = ald(pb + (size_t)s7 * 8 + jp);
            acc.x += bf2f(u0 & 0xFFFFu) + bf2f(u1 & 0xFFFFu)
                   + bf2f(u2 & 0xFFFFu) + bf2f(u3 & 0xFFFFu)
                   + bf2f(u4 & 0xFFFFu) + bf2f(u5 & 0xFFFFu)
                   + bf2f(u6 & 0xFFFFu) + bf2f(u7 & 0xFFFFu);
            acc.y += bf2f(u0 >> 16) + bf2f(u1 >> 16) + bf2f(u2 >> 16) + bf2f(u3 >> 16)
                   + bf2f(u4 >> 16) + bf2f(u5 >> 16) + bf2f(u6 >> 16) + bf2f(u7 >> 16);
        }
        for (; e + 2 <= end; e += 2) {
            unsigned s0 = srt[e], s1 = srt[e + 1];
            unsigned u0 = ald(pb + (size_t)s0 * 8 + jp);
            unsigned u1 = ald(pb + (size_t)s1 * 8 + jp);
            acc.x += bf2f(u0 & 0xFFFFu) + bf2f(u1 & 0xFFFFu);
            acc.y += bf2f(u0 >> 16) + bf2f(u1 >> 16);
        }
        for (; e < end; ++e) {
            unsigned u = ald(pb + (size_t)srt[e] * 8 + jp);
            acc.x += bf2f(u & 0xFFFFu);
            acc.y += bf2f(u >> 16);
        }
        float ox = 0.f, oy = 0.f;
        if (gn < N) {
            unsigned qu = *(const unsigned*)(q2b + (size_t)gn * HID + 2 * jp);
            ox = acc.x + bf2f(qu & 0xFFFFu) + sb2[2 * jp];
            oy = acc.y + bf2f(qu >> 16) + sb2[2 * jp + 1];
        }
        float m = fmaxf(ox, oy);
#pragma unroll
        for (int mask = 1; mask < 8; mask <<= 1) m = fmaxf(m, __shfl_xor(m, mask, 8));
        float s = __expf(ox - m) + __expf(oy - m);
#pragma unroll
        for (int mask = 1; mask < 8; mask <<= 1) s += __shfl_xor(s, mask, 8);
        const float l = m + __logf(s);
        if (gn < N) {
            if (bf) ((unsigned*)out)[(size_t)gn * 8 + jp] = pack2(ox - l, oy - l);
            else    ((float2*)out)[(size_t)gn * 8 + jp] = make_float2(ox - l, oy - l);
        }
    }
}

// ---------- fallback split path (round-1, known correct) ----------
__global__ __launch_bounds__(256) void k_sagg1(const unsigned* __restrict__ eb,
                                               const int* __restrict__ gcur,
                                               const unsigned short* __restrict__ p1b,
                                               const unsigned short* __restrict__ q1b,
                                               const void* __restrict__ b1,
                                               const void* __restrict__ w2rel,
                                               const void* __restrict__ w2root,
                                               unsigned short* __restrict__ p2b,
                                               unsigned short* __restrict__ q2b,
                                               unsigned* __restrict__ csr,
                                               int* __restrict__ offsets,
                                               int* __restrict__ ends,
                                               const int* __restrict__ flags,
                                               int N) {
    __shared__ unsigned srt[CAP];
    __shared__ int cnts[BKT_NODES];
    __shared__ int offs[BKT_NODES];
    __shared__ float4 swp[HID][8];
    __shared__ float sb[HID];
    const int t = threadIdx.x;
    const int b = blockIdx.x;
    const int bf = flags[0];

    if (t < 128) {
        int k = t >> 3, p = t & 7;
        float4 w;
        if (bf) {
            const unsigned short* a = (const unsigned short*)w2rel;
            const unsigned short* c = (const unsigned short*)w2root;
            w = make_float4(bf2f(a[k * 16 + 2 * p]), bf2f(a[k * 16 + 2 * p + 1]),
                            bf2f(c[k * 16 + 2 * p]), bf2f(c[k * 16 + 2 * p + 1]));
        } else {
            const float* a = (const float*)w2rel;
            const float* c = (const float*)w2root;
            w = make_float4(a[k * 16 + 2 * p], a[k * 16 + 2 * p + 1],
                            c[k * 16 + 2 * p], c[k * 16 + 2 * p + 1]);
        }
        swp[k][p] = w;
    }
    if (t < HID) sb[t] = bf ? bf2f(((const unsigned short*)b1)[t]) : ((const float*)b1)[t];
    if (t < BKT_NODES) cnts[t] = 0;
    __syncthreads();

    int cnt = gcur[b];
    if (cnt < 0) cnt = 0;
    if (cnt > CAP) cnt = CAP;
    const unsigned* ep = eb + (size_t)b * CAP;

    unsigned ev[CAPI];
    int rk[CAPI];
#pragma unroll
    for (int i = 0; i < CAPI; ++i) {
        int e = i * 256 + t;
        if (e < cnt) {
            unsigned w = ep[e];
            ev[i] = w;
            rk[i] = atomicAdd(&cnts[w & (BKT_NODES - 1u)], 1);
        } else ev[i] = NOEDGE;
    }
    __syncthreads();
    if (t < BKT_NODES) offs[t] = cnts[t];
    __syncthreads();
    for (int off = 1; off < BKT_NODES; off <<= 1) {
        int v = 0;
        if (t >= off && t < BKT_NODES) v = offs[t - off];
        __syncthreads();
        if (t < BKT_NODES) offs[t] += v;
        __syncthreads();
    }
#pragma unroll
    for (int i = 0; i < CAPI; ++i) {
        if (ev[i] != NOEDGE) {
            unsigned local = ev[i] & (BKT_NODES - 1u);
            int pos = offs[local] - cnts[local] + rk[i];
            srt[pos] = ev[i] >> BKT_SHIFT;
        }
    }
    __syncthreads();

    const int base = b * CAP;
    for (int e = t; e < cnt; e += 256) csr[base + e] = srt[e];
    const int gb = b * BKT_NODES;
    if (t < BKT_NODES) {
        int gn = gb + t;
        if (gn < N) {
            offsets[gn] = base + offs[t] - cnts[t];
            ends[gn]    = base + offs[t];
        }
    }

    const int grp = t >> 3, jp = t & 7;
#pragma unroll
    for (int g = 0; g < 4; ++g) {
        int node = g * 32 + grp;
        int gn = gb + node;
        int beg = offs[node] - cnts[node];
        int end = offs[node];
        float2 acc = make_float2(0.f, 0.f);
        int e = beg;
        for (; e + 4 <= end; e += 4) {
            unsigned s0 = srt[e], s1 = srt[e + 1], s2 = srt[e + 2], s3 = srt[e + 3];
            unsigned u0 = *(const unsigned*)(p1b + (size_t)s0 * HID + 2 * jp);
            unsigned u1 = *(const unsigned*)(p1b + (size_t)s1 * HID + 2 * jp);
            unsigned u2 = *(const unsigned*)(p1b + (size_t)s2 * HID + 2 * jp);
            unsigned u3 = *(const unsigned*)(p1b + (size_t)s3 * HID + 2 * jp);
            acc.x += bf2f(u0 & 0xFFFFu) + bf2f(u1 & 0xFFFFu)
                   + bf2f(u2 & 0xFFFFu) + bf2f(u3 & 0xFFFFu);
            acc.y += bf2f(u0 >> 16) + bf2f(u1 >> 16) + bf2f(u2 >> 16) + bf2f(u3 >> 16);
        }
        for (; e < end; ++e) {
            unsigned u = *(const unsigned*)(p1b + (size_t)srt[e] * HID + 2 * jp);
            acc.x += bf2f(u & 0xFFFFu);
            acc.y += bf2f(u >> 16);
        }
        float hx = 0.f, hy = 0.f;
        if (gn < N) {
            unsigned qu = *(const unsigned*)(q1b + (size_t)gn * HID + 2 * jp);
            hx = fmaxf(acc.x + bf2f(qu & 0xFFFFu) + sb[2 * jp], 0.f);
            hy = fmaxf(acc.y + bf2f(qu >> 16) + sb[2 * jp + 1], 0.f);
        }
        float2 sp = make_float2(0.f, 0.f), sq = make_float2(0.f, 0.f);
#pragma unroll
        for (int k = 0; k < HID; ++k) {
            float hsel = (k & 1) ? hy : hx;
            float hk = __shfl(hsel, k >> 1, 8);
            float4 w = swp[k][jp];
            sp.x += hk * w.x; sp.y += hk * w.y;
            sq.x += hk * w.z; sq.y += hk * w.w;
        }
        if (gn < N) {
            ((unsigned*)p2b)[(size_t)gn * 8 + jp] = pack2(sp.x, sp.y);
            ((unsigned*)q2b)[(size_t)gn * 8 + jp] = pack2(sq.x, sq.y);
        }
    }
}

__global__ __launch_bounds__(256) void k_agg2(const int* __restrict__ offsets,
                                              const int* __restrict__ ends,
                                              const unsigned* __restrict__ csr,
                                              const unsigned short* __restrict__ p2b,
                                              const unsigned short* __restrict__ q2b,
                                              const void* __restrict__ b2,
                                              void* __restrict__ out,
                                              const int* __restrict__ flags,
                                              int N) {
    __shared__ float sb[HID];
    const int t = threadIdx.x;
    const int bf = flags[0];
    if (t < HID) sb[t] = bf ? bf2f(((const unsigned short*)b2)[t]) : ((const float*)b2)[t];
    __syncthreads();

    const int grp = t >> 3, jp = t & 7;
    const int n = blockIdx.x * 32 + grp;
    if (n >= N) return;

    const int beg = offsets[n], end = ends[n];
    float2 acc = make_float2(0.f, 0.f);
    int e = beg;
    for (; e + 8 <= end; e += 8) {
        unsigned s0 = csr[e],     s1 = csr[e + 1], s2 = csr[e + 2], s3 = csr[e + 3];
        unsigned s4 = csr[e + 4], s5 = csr[e + 5], s6 = csr[e + 6], s7 = csr[e + 7];
        unsigned u0 = *(const unsigned*)(p2b + (size_t)s0 * HID + 2 * jp);
        unsigned u1 = *(const unsigned*)(p2b + (size_t)s1 * HID + 2 * jp);
        unsigned u2 = *(const unsigned*)(p2b + (size_t)s2 * HID + 2 * jp);
        unsigned u3 = *(const unsigned*)(p2b + (size_t)s3 * HID + 2 * jp);
        unsigned u4 = *(const unsigned*)(p2b + (size_t)s4 * HID + 2 * jp);
        unsigned u5 = *(const unsigned*)(p2b + (size_t)s5 * HID + 2 * jp);
        unsigned u6 = *(const unsigned*)(p2b + (size_t)s6 * HID + 2 * jp);
        unsigned u7 = *(const unsigned*)(p2b + (size_t)s7 * HID + 2 * jp);
        acc.x += bf2f(u0 & 0xFFFFu) + bf2f(u1 & 0xFFFFu)
               + bf2f(u2 & 0xFFFFu) + bf2f(u3 & 0xFFFFu)
               + bf2f(u4 & 0xFFFFu) + bf2f(u5 & 0xFFFFu)
               + bf2f(u6 & 0xFFFFu) + bf2f(u7 & 0xFFFFu);
        acc.y += bf2f(u0 >> 16) + bf2f(u1 >> 16) + bf2f(u2 >> 16) + bf2f(u3 >> 16)
               + bf2f(u4 >> 16) + bf2f(u5 >> 16) + bf2f(u6 >> 16) + bf2f(u7 >> 16);
    }
    for (; e + 2 <= end; e += 2) {
        unsigned s0 = csr[e], s1 = csr[e + 1];
        unsigned u0 = *(const unsigned*)(p2b + (size_t)s0 * HID + 2 * jp);
        unsigned u1 = *(const unsigned*)(p2b + (size_t)s1 * HID + 2 * jp);
        acc.x += bf2f(u0 & 0xFFFFu) + bf2f(u1 & 0xFFFFu);
        acc.y += bf2f(u0 >> 16) + bf2f(u1 >> 16);
    }
    for (; e < end; ++e) {
        unsigned u = *(const unsigned*)(p2b + (size_t)csr[e] * HID + 2 * jp);
        acc.x += bf2f(u & 0xFFFFu);
        acc.y += bf2f(u >> 16);
    }
    unsigned qu = *(const unsigned*)(q2b + (size_t)n * HID + 2 * jp);
    float ox = acc.x + bf2f(qu & 0xFFFFu) + sb[2 * jp];
    float oy = acc.y + bf2f(qu >> 16) + sb[2 * jp + 1];

    float m = fmaxf(ox, oy);
#pragma unroll
    for (int mask = 1; mask < 8; mask <<= 1) m = fmaxf(m, __shfl_xor(m, mask, 8));
    float s = __expf(ox - m) + __expf(oy - m);
#pragma unroll
    for (int mask = 1; mask < 8; mask <<= 1) s += __shfl_xor(s, mask, 8);
    const float l = m + __logf(s);

    if (bf) ((unsigned*)out)[(size_t)n * 8 + jp] = pack2(ox - l, oy - l);
    else    ((float2*)out)[(size_t)n * 8 + jp] = make_float2(ox - l, oy - l);
}

extern "C" void kernel_launch(void* const* d_in, const int* in_sizes, int n_in,
                              void* d_out, int out_size, void* d_ws, size_t ws_size,
                              hipStream_t stream) {
    const void* x       = d_in[0];
    const int*  ei      = (const int*)d_in[1];
    const void* w1_rel  = d_in[2];
    const void* w1_root = d_in[3];
    const void* b1      = d_in[4];
    const void* w2_rel  = d_in[5];
    const void* w2_root = d_in[6];
    const void* b2      = d_in[7];

    const int N = in_sizes[0] / DFEAT;                       // 100000
    const int E = in_sizes[1] / 2;                           // 1600000
    const int nbkt = (N + BKT_NODES - 1) / BKT_NODES;        // 782

    unsigned short* p1b = (unsigned short*)d_ws;
    unsigned short* q1b = p1b + (size_t)N * HID;
    unsigned short* p2b = q1b + (size_t)N * HID;
    unsigned short* q2b = p2b + (size_t)N * HID;
    unsigned* eb   = (unsigned*)(q2b + (size_t)N * HID);     // nbkt*CAP u32
    unsigned* csr  = eb + (size_t)nbkt * CAP;                // nbkt*CAP u32 (fallback)
    int* offsets   = (int*)(csr + (size_t)nbkt * CAP);       // N (fallback)
    int* ends      = offsets + N;                            // N (fallback)
    int* gcur      = ends + N;                               // nbkt
    int* flags     = gcur + nbkt;                            // 2

    const int nPart = (E + CHUNK - 1) / CHUNK;               // 391
    const int nLin  = (N + 63) / 64;                         // 1563

    k_detect<<<1, 512, 0, stream>>>((const unsigned short*)x, ei, flags, gcur, nbkt);
    k_pl<<<nPart + nLin, 256, 0, stream>>>(ei, eb, gcur, x, w1_rel, w1_root,
                                           p1b, q1b, flags, E, nbkt, N, nPart);

    int dev = 0, coop = 0;
    hipGetDevice(&dev);
    hipDeviceGetAttribute(&coop, hipDeviceAttributeCooperativeLaunch, dev);

    hipError_t err = hipErrorUnknown;
    if (coop) {
        const unsigned* eb_a        = eb;
        const int* gcur_a           = gcur;
        const unsigned short* p1b_a = p1b;
        const unsigned short* q1b_a = q1b;
        const void* b1_a            = b1;
        const void* w2rel_a         = w2_rel;
        const void* w2root_a        = w2_root;
        unsigned short* p2b_a       = p2b;
        unsigned short* q2b_a       = q2b;
        const void* b2_a            = b2;
        void* out_a                 = d_out;
        const int* flags_a          = flags;
        int N_a                     = N;
        void* args[] = {&eb_a, &gcur_a, &p1b_a, &q1b_a, &b1_a, &w2rel_a, &w2root_a,
                        &p2b_a, &q2b_a, &b2_a, &out_a, &flags_a, &N_a};
        err = hipLaunchCooperativeKernel((void*)k_sagg, dim3(nbkt), dim3(256),
                                         args, 0, stream);
    }
    if (err != hipSuccess) {
        // split fallback (kernel boundary = device-scope release/acquire)
        k_sagg1<<<nbkt, 256, 0, stream>>>(eb, gcur, p1b, q1b, b1, w2_rel, w2_root,
                                          p2b, q2b, csr, offsets, ends, flags, N);
        k_agg2<<<(N + 31) / 32, 256, 0, stream>>>(offsets, ends, csr, p2b, q2b, b2,
                                                  d_out, flags, N);
    }
}

// Round 4
// 183.145 us; speedup vs baseline: 1.8956x; 1.8956x over previous
//
#include <hip/hip_runtime.h>

#define DFEAT 128
#define HID 16
#define BKT_NODES 64       // dst nodes per bucket -> nbkt=1563 (~6 blocks/CU)
#define BKT_SHIFT 6
#define CAP 1280           // mean 1024 + 8 sigma
#define CAPI 5             // CAP/256 register-cache iterations
#define CHUNK 2048         // edges per partition block -> 782 blocks
#define NOEDGE 0xFFFFFFFFu

typedef __attribute__((ext_vector_type(8))) short short8;
typedef __attribute__((ext_vector_type(4))) float floatx4;

__device__ __forceinline__ float bf2f(unsigned v) { return __uint_as_float(v << 16); }
__device__ __forceinline__ unsigned short f2bf(float f) {
    unsigned u = __float_as_uint(f);
    return (unsigned short)((u + 0x7FFFu + ((u >> 16) & 1u)) >> 16);
}
__device__ __forceinline__ unsigned pack2(float a, float b) {
    return (unsigned)f2bf(a) | ((unsigned)f2bf(b) << 16);
}

// flags[0]=1 if float tensors are bf16; flags[1]=1 if edge_index is int64.
// Also zeros gcur (kernel, not hipMemsetAsync — graph-capture safe).
__global__ __launch_bounds__(512) void k_detect(const unsigned short* __restrict__ x,
                                                const int* __restrict__ ei,
                                                int* __restrict__ flags,
                                                int* __restrict__ gcur, int nbkt) {
    const int t = threadIdx.x;
    for (int i = t; i < nbkt; i += 512) gcur[i] = 0;
    if (t < 64) {
        unsigned short v = x[2 * t];
        int e = (v >> 7) & 0xFF;
        bool okbf = (v == 0) || (e >= 110 && e <= 130);
        unsigned long long mbf = __ballot(okbf);
        bool z = (ei[2 * t + 1] == 0);
        unsigned long long mz = __ballot(z);
        if (t == 0) {
            flags[0] = (__popcll(mbf) >= 52) ? 1 : 0;
            flags[1] = (__popcll(mz) >= 60) ? 1 : 0;
        }
    }
}

// FUSED: edge partition (blocks [0, nPart)) + layer-1 projection (rest).
// Partition: 2048 edges/block (782 blocks — round-1's 391 ran long-tailed
// at ~1.5/CU; partition was k_pl's long pole). Lin1: 32 nodes/wave (2 MFMA
// tiles) — 8 A-loads in flight, weight regs amortized over 16 MFMAs.
__global__ __launch_bounds__(256) void k_pl(const int* __restrict__ ei,
                                            unsigned* __restrict__ eb,
                                            int* __restrict__ gcur,
                                            const void* __restrict__ xv,
                                            const void* __restrict__ wrel,
                                            const void* __restrict__ wroot,
                                            unsigned short* __restrict__ p1b,
                                            unsigned short* __restrict__ q1b,
                                            const int* __restrict__ flags,
                                            int E, int nbkt, int N, int nPart) {
    __shared__ int hist[2048];         // nbkt <= 2048
    const int t = threadIdx.x;

    if ((int)blockIdx.x < nPart) {
        // ---------------- edge partition path ----------------
        for (int i = t; i < nbkt; i += 256) hist[i] = 0;
        __syncthreads();
        const int base = blockIdx.x * CHUNK;
        const int i64 = flags[1];
        unsigned pk[8];
        unsigned short bk[8];
        if (i64 && !(E & 1)) {
            // int64 path: one dwordx4 per edge-pair for src and dst each.
#pragma unroll
            for (int ip = 0; ip < 4; ++ip) {
                int e = base + ip * 512 + 2 * t;
                if (e < E) {   // E even, e even -> e+1 < E too
                    int4 sv = *(const int4*)(ei + 2 * (size_t)e);
                    int4 dv = *(const int4*)(ei + 2 * ((size_t)E + e));
                    int b0 = dv.x >> BKT_SHIFT;
                    pk[2 * ip] = ((unsigned)sv.x << BKT_SHIFT) | (unsigned)(dv.x & (BKT_NODES - 1));
                    bk[2 * ip] = (unsigned short)b0;
                    atomicAdd(&hist[b0], 1);
                    int b1 = dv.z >> BKT_SHIFT;
                    pk[2 * ip + 1] = ((unsigned)sv.z << BKT_SHIFT) | (unsigned)(dv.z & (BKT_NODES - 1));
                    bk[2 * ip + 1] = (unsigned short)b1;
                    atomicAdd(&hist[b1], 1);
                } else {
                    bk[2 * ip] = 0xFFFFu;
                    bk[2 * ip + 1] = 0xFFFFu;
                }
            }
        } else {
#pragma unroll
            for (int i = 0; i < 8; ++i) {
                int e = base + i * 256 + t;
                if (e < E) {
                    int src, dst;
                    if (i64) { src = ei[2 * (size_t)e]; dst = ei[2 * ((size_t)E + e)]; }
                    else     { src = ei[e];             dst = ei[(size_t)E + e]; }
                    int b = dst >> BKT_SHIFT;
                    pk[i] = ((unsigned)src << BKT_SHIFT) | (unsigned)(dst & (BKT_NODES - 1));
                    bk[i] = (unsigned short)b;
                    atomicAdd(&hist[b], 1);
                } else {
                    bk[i] = 0xFFFFu;
                }
            }
        }
        __syncthreads();
        for (int b = t; b < nbkt; b += 256) {
            int c = hist[b];
            hist[b] = c ? atomicAdd(&gcur[b], c) : 0;
        }
        __syncthreads();
#pragma unroll
        for (int i = 0; i < 8; ++i) {
            if (bk[i] != 0xFFFFu) {
                int pos = atomicAdd(&hist[bk[i]], 1);
                if (pos >= 0 && pos < CAP)
                    eb[(size_t)bk[i] * CAP + pos] = pk[i];
            }
        }
        return;
    }

    // ---------------- layer-1 projection path ----------------
    // p1b = bf16(x @ w1_rel), q1b = bf16(x @ w1_root); 2 tiles (32 nodes)
    // per wave, 128 nodes per block.
    const int lane = t & 63, wave = t >> 6;
    const int bf = flags[0];
    const int m = lane & 15;
    const int quad = lane >> 4;
    const int nodebase = ((int)blockIdx.x - nPart) * 128 + wave * 32;

    short8 Brel[4], Broot[4];
    if (bf) {
        const unsigned short* a = (const unsigned short*)wrel;
        const unsigned short* c = (const unsigned short*)wroot;
#pragma unroll
        for (int kb = 0; kb < 4; ++kb) {
            short8 br, bo;
#pragma unroll
            for (int j = 0; j < 8; ++j) {
                int k = kb * 32 + quad * 8 + j;
                br[j] = (short)a[k * HID + m];
                bo[j] = (short)c[k * HID + m];
            }
            Brel[kb] = br; Broot[kb] = bo;
        }
    } else {
        const float* a = (const float*)wrel;
        const float* c = (const float*)wroot;
#pragma unroll
        for (int kb = 0; kb < 4; ++kb) {
            short8 br, bo;
#pragma unroll
            for (int j = 0; j < 8; ++j) {
                int k = kb * 32 + quad * 8 + j;
                br[j] = (short)f2bf(a[k * HID + m]);
                bo[j] = (short)f2bf(c[k * HID + m]);
            }
            Brel[kb] = br; Broot[kb] = bo;
        }
    }

    int row0 = nodebase + m;           if (row0 >= N) row0 = N - 1;
    int row1 = nodebase + 16 + m;      if (row1 >= N) row1 = N - 1;

    floatx4 accP0 = {0.f, 0.f, 0.f, 0.f}, accQ0 = {0.f, 0.f, 0.f, 0.f};
    floatx4 accP1 = {0.f, 0.f, 0.f, 0.f}, accQ1 = {0.f, 0.f, 0.f, 0.f};
    if (bf) {
        const unsigned short* xp = (const unsigned short*)xv;
        const unsigned short* rp0 = xp + (size_t)row0 * DFEAT + quad * 8;
        const unsigned short* rp1 = xp + (size_t)row1 * DFEAT + quad * 8;
        short8 A0[4], A1[4];
#pragma unroll
        for (int kb = 0; kb < 4; ++kb) A0[kb] = *(const short8*)(rp0 + kb * 32);
#pragma unroll
        for (int kb = 0; kb < 4; ++kb) A1[kb] = *(const short8*)(rp1 + kb * 32);
#pragma unroll
        for (int kb = 0; kb < 4; ++kb) {
            accP0 = __builtin_amdgcn_mfma_f32_16x16x32_bf16(A0[kb], Brel[kb], accP0, 0, 0, 0);
            accQ0 = __builtin_amdgcn_mfma_f32_16x16x32_bf16(A0[kb], Broot[kb], accQ0, 0, 0, 0);
            accP1 = __builtin_amdgcn_mfma_f32_16x16x32_bf16(A1[kb], Brel[kb], accP1, 0, 0, 0);
            accQ1 = __builtin_amdgcn_mfma_f32_16x16x32_bf16(A1[kb], Broot[kb], accQ1, 0, 0, 0);
        }
    } else {
        const float* xp = (const float*)xv;
        const float* rp0 = xp + (size_t)row0 * DFEAT + quad * 8;
        const float* rp1 = xp + (size_t)row1 * DFEAT + quad * 8;
#pragma unroll
        for (int kb = 0; kb < 4; ++kb) {
            float4 v0 = *(const float4*)(rp0 + kb * 32);
            float4 v1 = *(const float4*)(rp0 + kb * 32 + 4);
            float4 w0 = *(const float4*)(rp1 + kb * 32);
            float4 w1 = *(const float4*)(rp1 + kb * 32 + 4);
            short8 A0, A1;
            A0[0] = (short)f2bf(v0.x); A0[1] = (short)f2bf(v0.y);
            A0[2] = (short)f2bf(v0.z); A0[3] = (short)f2bf(v0.w);
            A0[4] = (short)f2bf(v1.x); A0[5] = (short)f2bf(v1.y);
            A0[6] = (short)f2bf(v1.z); A0[7] = (short)f2bf(v1.w);
            A1[0] = (short)f2bf(w0.x); A1[1] = (short)f2bf(w0.y);
            A1[2] = (short)f2bf(w0.z); A1[3] = (short)f2bf(w0.w);
            A1[4] = (short)f2bf(w1.x); A1[5] = (short)f2bf(w1.y);
            A1[6] = (short)f2bf(w1.z); A1[7] = (short)f2bf(w1.w);
            accP0 = __builtin_amdgcn_mfma_f32_16x16x32_bf16(A0, Brel[kb], accP0, 0, 0, 0);
            accQ0 = __builtin_amdgcn_mfma_f32_16x16x32_bf16(A0, Broot[kb], accQ0, 0, 0, 0);
            accP1 = __builtin_amdgcn_mfma_f32_16x16x32_bf16(A1, Brel[kb], accP1, 0, 0, 0);
            accQ1 = __builtin_amdgcn_mfma_f32_16x16x32_bf16(A1, Broot[kb], accQ1, 0, 0, 0);
        }
    }

#pragma unroll
    for (int r = 0; r < 4; ++r) {
        int node0 = nodebase + quad * 4 + r;
        if (node0 < N) {
            p1b[(size_t)node0 * HID + m] = f2bf(accP0[r]);
            q1b[(size_t)node0 * HID + m] = f2bf(accQ0[r]);
        }
        int node1 = nodebase + 16 + quad * 4 + r;
        if (node1 < N) {
            p1b[(size_t)node1 * HID + m] = f2bf(accP1[r]);
            q1b[(size_t)node1 * HID + m] = f2bf(accQ1[r]);
        }
    }
}

// Fused counting-sort + layer-1 aggregate + epilogue; one block per 64-node
// bucket (1563 blocks ~6/CU). csr/offsets/ends published for k_agg2.
__global__ __launch_bounds__(256) void k_sagg1(const unsigned* __restrict__ eb,
                                               const int* __restrict__ gcur,
                                               const unsigned short* __restrict__ p1b,
                                               const unsigned short* __restrict__ q1b,
                                               const void* __restrict__ b1,
                                               const void* __restrict__ w2rel,
                                               const void* __restrict__ w2root,
                                               unsigned short* __restrict__ p2b,
                                               unsigned short* __restrict__ q2b,
                                               unsigned* __restrict__ csr,
                                               int* __restrict__ offsets,
                                               int* __restrict__ ends,
                                               const int* __restrict__ flags,
                                               int N) {
    __shared__ unsigned srt[CAP];       // 5 KB
    __shared__ int cnts[BKT_NODES];
    __shared__ int offs[BKT_NODES];
    __shared__ float4 swp[HID][8];      // {rel_j0, rel_j1, root_j0, root_j1}
    __shared__ float sb[HID];
    const int t = threadIdx.x;
    const int b = blockIdx.x;
    const int bf = flags[0];

    if (t < 128) {
        int k = t >> 3, p = t & 7;
        float4 w;
        if (bf) {
            const unsigned short* a = (const unsigned short*)w2rel;
            const unsigned short* c = (const unsigned short*)w2root;
            w = make_float4(bf2f(a[k * 16 + 2 * p]), bf2f(a[k * 16 + 2 * p + 1]),
                            bf2f(c[k * 16 + 2 * p]), bf2f(c[k * 16 + 2 * p + 1]));
        } else {
            const float* a = (const float*)w2rel;
            const float* c = (const float*)w2root;
            w = make_float4(a[k * 16 + 2 * p], a[k * 16 + 2 * p + 1],
                            c[k * 16 + 2 * p], c[k * 16 + 2 * p + 1]);
        }
        swp[k][p] = w;
    }
    if (t < HID) sb[t] = bf ? bf2f(((const unsigned short*)b1)[t]) : ((const float*)b1)[t];
    if (t < BKT_NODES) cnts[t] = 0;
    __syncthreads();

    int cnt = gcur[b];
    if (cnt < 0) cnt = 0;
    if (cnt > CAP) cnt = CAP;
    const unsigned* ep = eb + (size_t)b * CAP;

    unsigned ev[CAPI];
    int rk[CAPI];
#pragma unroll
    for (int i = 0; i < CAPI; ++i) {
        int e = i * 256 + t;
        if (e < cnt) {
            unsigned w = ep[e];
            ev[i] = w;
            rk[i] = atomicAdd(&cnts[w & (BKT_NODES - 1u)], 1);
        } else ev[i] = NOEDGE;
    }
    __syncthreads();
    // inclusive scan of counts (threads [0,64) active; barriers uniform)
    if (t < BKT_NODES) offs[t] = cnts[t];
    __syncthreads();
    for (int off = 1; off < BKT_NODES; off <<= 1) {
        int v = 0;
        if (t >= off && t < BKT_NODES) v = offs[t - off];
        __syncthreads();
        if (t < BKT_NODES) offs[t] += v;
        __syncthreads();
    }
#pragma unroll
    for (int i = 0; i < CAPI; ++i) {
        if (ev[i] != NOEDGE) {
            unsigned local = ev[i] & (BKT_NODES - 1u);
            int pos = offs[local] - cnts[local] + rk[i];   // exclusive + rank
            srt[pos] = ev[i] >> BKT_SHIFT;
        }
    }
    __syncthreads();

    // publish CSR for k_agg2 (fixed-stride base, coalesced)
    const int base = b * CAP;
    for (int e = t; e < cnt; e += 256) csr[base + e] = srt[e];
    const int gb = b * BKT_NODES;
    if (t < BKT_NODES) {
        int gn = gb + t;
        if (gn < N) {
            offsets[gn] = base + offs[t] - cnts[t];
            ends[gn]    = base + offs[t];
        }
    }

    // layer-1 aggregate from LDS srt + fused relu/bias/matmuls.
    const int grp = t >> 3, jp = t & 7;   // 32 groups; 64 nodes -> 2 per group
#pragma unroll
    for (int g = 0; g < 2; ++g) {
        int node = g * 32 + grp;
        int gn = gb + node;
        int beg = offs[node] - cnts[node];
        int end = offs[node];
        float2 acc = make_float2(0.f, 0.f);
        int e = beg;
        for (; e + 4 <= end; e += 4) {
            unsigned s0 = srt[e], s1 = srt[e + 1], s2 = srt[e + 2], s3 = srt[e + 3];
            unsigned u0 = *(const unsigned*)(p1b + (size_t)s0 * HID + 2 * jp);
            unsigned u1 = *(const unsigned*)(p1b + (size_t)s1 * HID + 2 * jp);
            unsigned u2 = *(const unsigned*)(p1b + (size_t)s2 * HID + 2 * jp);
            unsigned u3 = *(const unsigned*)(p1b + (size_t)s3 * HID + 2 * jp);
            acc.x += bf2f(u0 & 0xFFFFu) + bf2f(u1 & 0xFFFFu)
                   + bf2f(u2 & 0xFFFFu) + bf2f(u3 & 0xFFFFu);
            acc.y += bf2f(u0 >> 16) + bf2f(u1 >> 16) + bf2f(u2 >> 16) + bf2f(u3 >> 16);
        }
        for (; e < end; ++e) {
            unsigned u = *(const unsigned*)(p1b + (size_t)srt[e] * HID + 2 * jp);
            acc.x += bf2f(u & 0xFFFFu);
            acc.y += bf2f(u >> 16);
        }
        float hx = 0.f, hy = 0.f;
        if (gn < N) {
            unsigned qu = *(const unsigned*)(q1b + (size_t)gn * HID + 2 * jp);
            hx = fmaxf(acc.x + bf2f(qu & 0xFFFFu) + sb[2 * jp], 0.f);
            hy = fmaxf(acc.y + bf2f(qu >> 16) + sb[2 * jp + 1], 0.f);
        }
        float2 sp = make_float2(0.f, 0.f), sq = make_float2(0.f, 0.f);
#pragma unroll
        for (int k = 0; k < HID; ++k) {
            float hsel = (k & 1) ? hy : hx;
            float hk = __shfl(hsel, k >> 1, 8);
            float4 w = swp[k][jp];
            sp.x += hk * w.x; sp.y += hk * w.y;
            sq.x += hk * w.z; sq.y += hk * w.w;
        }
        if (gn < N) {
            ((unsigned*)p2b)[(size_t)gn * 8 + jp] = pack2(sp.x, sp.y);
            ((unsigned*)q2b)[(size_t)gn * 8 + jp] = pack2(sq.x, sq.y);
        }
    }
}

// Layer 2 aggregate via CSR + log_softmax epilogue. Unroll-8 gather.
__global__ __launch_bounds__(256) void k_agg2(const int* __restrict__ offsets,
                                              const int* __restrict__ ends,
                                              const unsigned* __restrict__ csr,
                                              const unsigned short* __restrict__ p2b,
                                              const unsigned short* __restrict__ q2b,
                                              const void* __restrict__ b2,
                                              void* __restrict__ out,
                                              const int* __restrict__ flags,
                                              int N) {
    __shared__ float sb[HID];
    const int t = threadIdx.x;
    const int bf = flags[0];
    if (t < HID) sb[t] = bf ? bf2f(((const unsigned short*)b2)[t]) : ((const float*)b2)[t];
    __syncthreads();

    const int grp = t >> 3, jp = t & 7;
    const int n = blockIdx.x * 32 + grp;
    if (n >= N) return;

    const int beg = offsets[n], end = ends[n];
    float2 acc = make_float2(0.f, 0.f);
    int e = beg;
    for (; e + 8 <= end; e += 8) {
        unsigned s0 = csr[e],     s1 = csr[e + 1], s2 = csr[e + 2], s3 = csr[e + 3];
        unsigned s4 = csr[e + 4], s5 = csr[e + 5], s6 = csr[e + 6], s7 = csr[e + 7];
        unsigned u0 = *(const unsigned*)(p2b + (size_t)s0 * HID + 2 * jp);
        unsigned u1 = *(const unsigned*)(p2b + (size_t)s1 * HID + 2 * jp);
        unsigned u2 = *(const unsigned*)(p2b + (size_t)s2 * HID + 2 * jp);
        unsigned u3 = *(const unsigned*)(p2b + (size_t)s3 * HID + 2 * jp);
        unsigned u4 = *(const unsigned*)(p2b + (size_t)s4 * HID + 2 * jp);
        unsigned u5 = *(const unsigned*)(p2b + (size_t)s5 * HID + 2 * jp);
        unsigned u6 = *(const unsigned*)(p2b + (size_t)s6 * HID + 2 * jp);
        unsigned u7 = *(const unsigned*)(p2b + (size_t)s7 * HID + 2 * jp);
        acc.x += bf2f(u0 & 0xFFFFu) + bf2f(u1 & 0xFFFFu)
               + bf2f(u2 & 0xFFFFu) + bf2f(u3 & 0xFFFFu)
               + bf2f(u4 & 0xFFFFu) + bf2f(u5 & 0xFFFFu)
               + bf2f(u6 & 0xFFFFu) + bf2f(u7 & 0xFFFFu);
        acc.y += bf2f(u0 >> 16) + bf2f(u1 >> 16) + bf2f(u2 >> 16) + bf2f(u3 >> 16)
               + bf2f(u4 >> 16) + bf2f(u5 >> 16) + bf2f(u6 >> 16) + bf2f(u7 >> 16);
    }
    for (; e + 2 <= end; e += 2) {
        unsigned s0 = csr[e], s1 = csr[e + 1];
        unsigned u0 = *(const unsigned*)(p2b + (size_t)s0 * HID + 2 * jp);
        unsigned u1 = *(const unsigned*)(p2b + (size_t)s1 * HID + 2 * jp);
        acc.x += bf2f(u0 & 0xFFFFu) + bf2f(u1 & 0xFFFFu);
        acc.y += bf2f(u0 >> 16) + bf2f(u1 >> 16);
    }
    for (; e < end; ++e) {
        unsigned u = *(const unsigned*)(p2b + (size_t)csr[e] * HID + 2 * jp);
        acc.x += bf2f(u & 0xFFFFu);
        acc.y += bf2f(u >> 16);
    }
    unsigned qu = *(const unsigned*)(q2b + (size_t)n * HID + 2 * jp);
    float ox = acc.x + bf2f(qu & 0xFFFFu) + sb[2 * jp];
    float oy = acc.y + bf2f(qu >> 16) + sb[2 * jp + 1];

    float m = fmaxf(ox, oy);
#pragma unroll
    for (int mask = 1; mask < 8; mask <<= 1) m = fmaxf(m, __shfl_xor(m, mask, 8));
    float s = __expf(ox - m) + __expf(oy - m);
#pragma unroll
    for (int mask = 1; mask < 8; mask <<= 1) s += __shfl_xor(s, mask, 8);
    const float l = m + __logf(s);

    if (bf) ((unsigned*)out)[(size_t)n * 8 + jp] = pack2(ox - l, oy - l);
    else    ((float2*)out)[(size_t)n * 8 + jp] = make_float2(ox - l, oy - l);
}

extern "C" void kernel_launch(void* const* d_in, const int* in_sizes, int n_in,
                              void* d_out, int out_size, void* d_ws, size_t ws_size,
                              hipStream_t stream) {
    const void* x       = d_in[0];
    const int*  ei      = (const int*)d_in[1];
    const void* w1_rel  = d_in[2];
    const void* w1_root = d_in[3];
    const void* b1      = d_in[4];
    const void* w2_rel  = d_in[5];
    const void* w2_root = d_in[6];
    const void* b2      = d_in[7];

    const int N = in_sizes[0] / DFEAT;                       // 100000
    const int E = in_sizes[1] / 2;                           // 1600000
    const int nbkt = (N + BKT_NODES - 1) / BKT_NODES;        // 1563

    unsigned short* p1b = (unsigned short*)d_ws;
    unsigned short* q1b = p1b + (size_t)N * HID;
    unsigned short* p2b = q1b + (size_t)N * HID;
    unsigned short* q2b = p2b + (size_t)N * HID;
    unsigned* eb   = (unsigned*)(q2b + (size_t)N * HID);     // nbkt*CAP u32
    unsigned* csr  = eb + (size_t)nbkt * CAP;                // nbkt*CAP u32
    int* offsets   = (int*)(csr + (size_t)nbkt * CAP);       // N
    int* ends      = offsets + N;                            // N
    int* gcur      = ends + N;                               // nbkt
    int* flags     = gcur + nbkt;                            // 2

    const int nPart = (E + CHUNK - 1) / CHUNK;               // 782
    const int nLin  = (N + 127) / 128;                       // 782

    k_detect<<<1, 512, 0, stream>>>((const unsigned short*)x, ei, flags, gcur, nbkt);
    k_pl<<<nPart + nLin, 256, 0, stream>>>(ei, eb, gcur, x, w1_rel, w1_root,
                                           p1b, q1b, flags, E, nbkt, N, nPart);
    k_sagg1<<<nbkt, 256, 0, stream>>>(eb, gcur, p1b, q1b, b1, w2_rel, w2_root,
                                      p2b, q2b, csr, offsets, ends, flags, N);
    k_agg2<<<(N + 31) / 32, 256, 0, stream>>>(offsets, ends, csr, p2b, q2b, b2,
                                              d_out, flags, N);
}

// Round 5
// 158.481 us; speedup vs baseline: 2.1905x; 1.1556x over previous
//
#include <hip/hip_runtime.h>

#define DFEAT 128
#define HID 16
#define BKT_NODES 128      // dst nodes per bucket -> nbkt=782
#define BKT_SHIFT 7
#define CAP 2432           // mean 2048 + ~8.5 sigma
#define CAPI 5             // ceil(CAP/512) register-cache iterations
#define CHUNK 8192         // edges per partition block -> 196 blocks
#define NOEDGE 0xFFFFFFFFu

typedef __attribute__((ext_vector_type(8))) short short8;
typedef __attribute__((ext_vector_type(4))) float floatx4;

__device__ __forceinline__ float bf2f(unsigned v) { return __uint_as_float(v << 16); }
__device__ __forceinline__ unsigned short f2bf(float f) {
    unsigned u = __float_as_uint(f);
    return (unsigned short)((u + 0x7FFFu + ((u >> 16) & 1u)) >> 16);
}
__device__ __forceinline__ unsigned pack2(float a, float b) {
    return (unsigned)f2bf(a) | ((unsigned)f2bf(b) << 16);
}

// flags[0]=1 if float tensors are bf16; flags[1]=1 if edge_index is int64.
// Also zeros gcur (kernel, not hipMemsetAsync — graph-capture safe).
__global__ __launch_bounds__(512) void k_detect(const unsigned short* __restrict__ x,
                                                const int* __restrict__ ei,
                                                int* __restrict__ flags,
                                                int* __restrict__ gcur, int nbkt) {
    const int t = threadIdx.x;
    for (int i = t; i < nbkt; i += 512) gcur[i] = 0;
    if (t < 64) {
        unsigned short v = x[2 * t];
        int e = (v >> 7) & 0xFF;
        bool okbf = (v == 0) || (e >= 110 && e <= 130);
        unsigned long long mbf = __ballot(okbf);
        bool z = (ei[2 * t + 1] == 0);
        unsigned long long mz = __ballot(z);
        if (t == 0) {
            flags[0] = (__popcll(mbf) >= 52) ? 1 : 0;
            flags[1] = (__popcll(mz) >= 60) ? 1 : 0;
        }
    }
}

// FUSED: edge partition (blocks [0, nPart)) + layer-1 projection (rest).
// Partition: 8192 edges/block, 128-node buckets -> ~21 contiguous edges per
// bucket per block => eb scatter amplification ~1.15x (round-4's 64-node/
// 2048-edge geometry hit ~12x: WRITE_SIZE 24->44 MB, +24 us). 512 threads.
__global__ __launch_bounds__(512) void k_pl(const int* __restrict__ ei,
                                            unsigned* __restrict__ eb,
                                            int* __restrict__ gcur,
                                            const void* __restrict__ xv,
                                            const void* __restrict__ wrel,
                                            const void* __restrict__ wroot,
                                            unsigned short* __restrict__ p1b,
                                            unsigned short* __restrict__ q1b,
                                            const int* __restrict__ flags,
                                            int E, int nbkt, int N, int nPart) {
    __shared__ int hist[1024];         // nbkt <= 1024
    const int t = threadIdx.x;

    if ((int)blockIdx.x < nPart) {
        // ---------------- edge partition path ----------------
        for (int i = t; i < nbkt; i += 512) hist[i] = 0;
        __syncthreads();
        const int base = blockIdx.x * CHUNK;
        const int i64 = flags[1];
        unsigned pk[16];
        unsigned short bk[16];
        if (i64 && !(E & 1)) {
            // int64 path: one dwordx4 per edge-pair for src and dst each.
#pragma unroll
            for (int ip = 0; ip < 8; ++ip) {
                int e = base + ip * 1024 + 2 * t;
                if (e < E) {   // E even, e even -> e+1 < E too
                    int4 sv = *(const int4*)(ei + 2 * (size_t)e);
                    int4 dv = *(const int4*)(ei + 2 * ((size_t)E + e));
                    int b0 = dv.x >> BKT_SHIFT;
                    pk[2 * ip] = ((unsigned)sv.x << BKT_SHIFT) | (unsigned)(dv.x & (BKT_NODES - 1));
                    bk[2 * ip] = (unsigned short)b0;
                    atomicAdd(&hist[b0], 1);
                    int b1 = dv.z >> BKT_SHIFT;
                    pk[2 * ip + 1] = ((unsigned)sv.z << BKT_SHIFT) | (unsigned)(dv.z & (BKT_NODES - 1));
                    bk[2 * ip + 1] = (unsigned short)b1;
                    atomicAdd(&hist[b1], 1);
                } else {
                    bk[2 * ip] = 0xFFFFu;
                    bk[2 * ip + 1] = 0xFFFFu;
                }
            }
        } else {
#pragma unroll
            for (int i = 0; i < 16; ++i) {
                int e = base + i * 512 + t;
                if (e < E) {
                    int src, dst;
                    if (i64) { src = ei[2 * (size_t)e]; dst = ei[2 * ((size_t)E + e)]; }
                    else     { src = ei[e];             dst = ei[(size_t)E + e]; }
                    int b = dst >> BKT_SHIFT;
                    pk[i] = ((unsigned)src << BKT_SHIFT) | (unsigned)(dst & (BKT_NODES - 1));
                    bk[i] = (unsigned short)b;
                    atomicAdd(&hist[b], 1);
                } else {
                    bk[i] = 0xFFFFu;
                }
            }
        }
        __syncthreads();
        for (int b = t; b < nbkt; b += 512) {
            int c = hist[b];
            hist[b] = c ? atomicAdd(&gcur[b], c) : 0;
        }
        __syncthreads();
#pragma unroll
        for (int i = 0; i < 16; ++i) {
            if (bk[i] != 0xFFFFu) {
                int pos = atomicAdd(&hist[bk[i]], 1);
                if (pos >= 0 && pos < CAP)
                    eb[(size_t)bk[i] * CAP + pos] = pk[i];
            }
        }
        return;
    }

    // ---------------- layer-1 projection path ----------------
    // p1b = bf16(x @ w1_rel), q1b = bf16(x @ w1_root); 16 nodes/wave,
    // 8 waves -> 128 nodes per block.
    const int lane = t & 63, wave = t >> 6;
    const int bf = flags[0];
    const int m = lane & 15;
    const int quad = lane >> 4;
    const int nodebase = ((int)blockIdx.x - nPart) * 128 + wave * 16;

    short8 Brel[4], Broot[4];
    if (bf) {
        const unsigned short* a = (const unsigned short*)wrel;
        const unsigned short* c = (const unsigned short*)wroot;
#pragma unroll
        for (int kb = 0; kb < 4; ++kb) {
            short8 br, bo;
#pragma unroll
            for (int j = 0; j < 8; ++j) {
                int k = kb * 32 + quad * 8 + j;
                br[j] = (short)a[k * HID + m];
                bo[j] = (short)c[k * HID + m];
            }
            Brel[kb] = br; Broot[kb] = bo;
        }
    } else {
        const float* a = (const float*)wrel;
        const float* c = (const float*)wroot;
#pragma unroll
        for (int kb = 0; kb < 4; ++kb) {
            short8 br, bo;
#pragma unroll
            for (int j = 0; j < 8; ++j) {
                int k = kb * 32 + quad * 8 + j;
                br[j] = (short)f2bf(a[k * HID + m]);
                bo[j] = (short)f2bf(c[k * HID + m]);
            }
            Brel[kb] = br; Broot[kb] = bo;
        }
    }

    int row = nodebase + m;
    if (row >= N) row = N - 1;

    floatx4 accP = {0.f, 0.f, 0.f, 0.f}, accQ = {0.f, 0.f, 0.f, 0.f};
    if (bf) {
        const unsigned short* xp = (const unsigned short*)xv;
        const unsigned short* rp = xp + (size_t)row * DFEAT + quad * 8;
#pragma unroll
        for (int kb = 0; kb < 4; ++kb) {
            short8 A = *(const short8*)(rp + kb * 32);
            accP = __builtin_amdgcn_mfma_f32_16x16x32_bf16(A, Brel[kb], accP, 0, 0, 0);
            accQ = __builtin_amdgcn_mfma_f32_16x16x32_bf16(A, Broot[kb], accQ, 0, 0, 0);
        }
    } else {
        const float* xp = (const float*)xv;
        const float* rp = xp + (size_t)row * DFEAT + quad * 8;
#pragma unroll
        for (int kb = 0; kb < 4; ++kb) {
            float4 v0 = *(const float4*)(rp + kb * 32);
            float4 v1 = *(const float4*)(rp + kb * 32 + 4);
            short8 A;
            A[0] = (short)f2bf(v0.x); A[1] = (short)f2bf(v0.y);
            A[2] = (short)f2bf(v0.z); A[3] = (short)f2bf(v0.w);
            A[4] = (short)f2bf(v1.x); A[5] = (short)f2bf(v1.y);
            A[6] = (short)f2bf(v1.z); A[7] = (short)f2bf(v1.w);
            accP = __builtin_amdgcn_mfma_f32_16x16x32_bf16(A, Brel[kb], accP, 0, 0, 0);
            accQ = __builtin_amdgcn_mfma_f32_16x16x32_bf16(A, Broot[kb], accQ, 0, 0, 0);
        }
    }

#pragma unroll
    for (int r = 0; r < 4; ++r) {
        int node = nodebase + quad * 4 + r;
        if (node < N) {
            p1b[(size_t)node * HID + m] = f2bf(accP[r]);
            q1b[(size_t)node * HID + m] = f2bf(accQ[r]);
        }
    }
}

// Fused counting-sort + layer-1 aggregate + epilogue; one 512-thread block
// per 128-node bucket (782 blocks x 8 waves ~24 waves/CU — round-1's
// 256-thread version capped at 12 waves/CU and was grid-occupancy-bound).
__global__ __launch_bounds__(512) void k_sagg1(const unsigned* __restrict__ eb,
                                               const int* __restrict__ gcur,
                                               const unsigned short* __restrict__ p1b,
                                               const unsigned short* __restrict__ q1b,
                                               const void* __restrict__ b1,
                                               const void* __restrict__ w2rel,
                                               const void* __restrict__ w2root,
                                               unsigned short* __restrict__ p2b,
                                               unsigned short* __restrict__ q2b,
                                               unsigned* __restrict__ csr,
                                               int* __restrict__ offsets,
                                               int* __restrict__ ends,
                                               const int* __restrict__ flags,
                                               int N) {
    __shared__ unsigned srt[CAP];       // 9.7 KB
    __shared__ int cnts[BKT_NODES];
    __shared__ int offs[BKT_NODES];
    __shared__ float4 swp[HID][8];      // {rel_j0, rel_j1, root_j0, root_j1}
    __shared__ float sb[HID];
    const int t = threadIdx.x;
    const int b = blockIdx.x;
    const int bf = flags[0];

    if (t < 128) {
        int k = t >> 3, p = t & 7;
        float4 w;
        if (bf) {
            const unsigned short* a = (const unsigned short*)w2rel;
            const unsigned short* c = (const unsigned short*)w2root;
            w = make_float4(bf2f(a[k * 16 + 2 * p]), bf2f(a[k * 16 + 2 * p + 1]),
                            bf2f(c[k * 16 + 2 * p]), bf2f(c[k * 16 + 2 * p + 1]));
        } else {
            const float* a = (const float*)w2rel;
            const float* c = (const float*)w2root;
            w = make_float4(a[k * 16 + 2 * p], a[k * 16 + 2 * p + 1],
                            c[k * 16 + 2 * p], c[k * 16 + 2 * p + 1]);
        }
        swp[k][p] = w;
    }
    if (t < HID) sb[t] = bf ? bf2f(((const unsigned short*)b1)[t]) : ((const float*)b1)[t];
    if (t < BKT_NODES) cnts[t] = 0;
    __syncthreads();

    int cnt = gcur[b];
    if (cnt < 0) cnt = 0;
    if (cnt > CAP) cnt = CAP;
    const unsigned* ep = eb + (size_t)b * CAP;

    unsigned ev[CAPI];
    int rk[CAPI];
#pragma unroll
    for (int i = 0; i < CAPI; ++i) {
        int e = i * 512 + t;
        if (e < cnt) {
            unsigned w = ep[e];
            ev[i] = w;
            rk[i] = atomicAdd(&cnts[w & (BKT_NODES - 1u)], 1);
        } else ev[i] = NOEDGE;
    }
    __syncthreads();
    // inclusive scan of counts (threads [0,128) active; barriers uniform)
    if (t < BKT_NODES) offs[t] = cnts[t];
    __syncthreads();
    for (int off = 1; off < BKT_NODES; off <<= 1) {
        int v = 0;
        if (t >= off && t < BKT_NODES) v = offs[t - off];
        __syncthreads();
        if (t < BKT_NODES) offs[t] += v;
        __syncthreads();
    }
#pragma unroll
    for (int i = 0; i < CAPI; ++i) {
        if (ev[i] != NOEDGE) {
            unsigned local = ev[i] & (BKT_NODES - 1u);
            int pos = offs[local] - cnts[local] + rk[i];   // exclusive + rank
            srt[pos] = ev[i] >> BKT_SHIFT;
        }
    }
    __syncthreads();

    // publish CSR for k_agg2 (fixed-stride base, coalesced)
    const int base = b * CAP;
    for (int e = t; e < cnt; e += 512) csr[base + e] = srt[e];
    const int gb = b * BKT_NODES;
    if (t < BKT_NODES) {
        int gn = gb + t;
        if (gn < N) {
            offsets[gn] = base + offs[t] - cnts[t];
            ends[gn]    = base + offs[t];
        }
    }

    // layer-1 aggregate from LDS srt + fused relu/bias/matmuls.
    const int grp = t >> 3, jp = t & 7;   // 64 groups; 128 nodes -> 2 per group
#pragma unroll
    for (int g = 0; g < 2; ++g) {
        int node = g * 64 + grp;
        int gn = gb + node;
        int beg = offs[node] - cnts[node];
        int end = offs[node];
        float2 acc = make_float2(0.f, 0.f);
        int e = beg;
        for (; e + 4 <= end; e += 4) {
            unsigned s0 = srt[e], s1 = srt[e + 1], s2 = srt[e + 2], s3 = srt[e + 3];
            unsigned u0 = *(const unsigned*)(p1b + (size_t)s0 * HID + 2 * jp);
            unsigned u1 = *(const unsigned*)(p1b + (size_t)s1 * HID + 2 * jp);
            unsigned u2 = *(const unsigned*)(p1b + (size_t)s2 * HID + 2 * jp);
            unsigned u3 = *(const unsigned*)(p1b + (size_t)s3 * HID + 2 * jp);
            acc.x += bf2f(u0 & 0xFFFFu) + bf2f(u1 & 0xFFFFu)
                   + bf2f(u2 & 0xFFFFu) + bf2f(u3 & 0xFFFFu);
            acc.y += bf2f(u0 >> 16) + bf2f(u1 >> 16) + bf2f(u2 >> 16) + bf2f(u3 >> 16);
        }
        for (; e < end; ++e) {
            unsigned u = *(const unsigned*)(p1b + (size_t)srt[e] * HID + 2 * jp);
            acc.x += bf2f(u & 0xFFFFu);
            acc.y += bf2f(u >> 16);
        }
        float hx = 0.f, hy = 0.f;
        if (gn < N) {
            unsigned qu = *(const unsigned*)(q1b + (size_t)gn * HID + 2 * jp);
            hx = fmaxf(acc.x + bf2f(qu & 0xFFFFu) + sb[2 * jp], 0.f);
            hy = fmaxf(acc.y + bf2f(qu >> 16) + sb[2 * jp + 1], 0.f);
        }
        float2 sp = make_float2(0.f, 0.f), sq = make_float2(0.f, 0.f);
#pragma unroll
        for (int k = 0; k < HID; ++k) {
            float hsel = (k & 1) ? hy : hx;
            float hk = __shfl(hsel, k >> 1, 8);
            float4 w = swp[k][jp];
            sp.x += hk * w.x; sp.y += hk * w.y;
            sq.x += hk * w.z; sq.y += hk * w.w;
        }
        if (gn < N) {
            ((unsigned*)p2b)[(size_t)gn * 8 + jp] = pack2(sp.x, sp.y);
            ((unsigned*)q2b)[(size_t)gn * 8 + jp] = pack2(sq.x, sq.y);
        }
    }
}

// Layer 2 aggregate via CSR + log_softmax epilogue. Unroll-8 gather.
__global__ __launch_bounds__(256) void k_agg2(const int* __restrict__ offsets,
                                              const int* __restrict__ ends,
                                              const unsigned* __restrict__ csr,
                                              const unsigned short* __restrict__ p2b,
                                              const unsigned short* __restrict__ q2b,
                                              const void* __restrict__ b2,
                                              void* __restrict__ out,
                                              const int* __restrict__ flags,
                                              int N) {
    __shared__ float sb[HID];
    const int t = threadIdx.x;
    const int bf = flags[0];
    if (t < HID) sb[t] = bf ? bf2f(((const unsigned short*)b2)[t]) : ((const float*)b2)[t];
    __syncthreads();

    const int grp = t >> 3, jp = t & 7;
    const int n = blockIdx.x * 32 + grp;
    if (n >= N) return;

    const int beg = offsets[n], end = ends[n];
    float2 acc = make_float2(0.f, 0.f);
    int e = beg;
    for (; e + 8 <= end; e += 8) {
        unsigned s0 = csr[e],     s1 = csr[e + 1], s2 = csr[e + 2], s3 = csr[e + 3];
        unsigned s4 = csr[e + 4], s5 = csr[e + 5], s6 = csr[e + 6], s7 = csr[e + 7];
        unsigned u0 = *(const unsigned*)(p2b + (size_t)s0 * HID + 2 * jp);
        unsigned u1 = *(const unsigned*)(p2b + (size_t)s1 * HID + 2 * jp);
        unsigned u2 = *(const unsigned*)(p2b + (size_t)s2 * HID + 2 * jp);
        unsigned u3 = *(const unsigned*)(p2b + (size_t)s3 * HID + 2 * jp);
        unsigned u4 = *(const unsigned*)(p2b + (size_t)s4 * HID + 2 * jp);
        unsigned u5 = *(const unsigned*)(p2b + (size_t)s5 * HID + 2 * jp);
        unsigned u6 = *(const unsigned*)(p2b + (size_t)s6 * HID + 2 * jp);
        unsigned u7 = *(const unsigned*)(p2b + (size_t)s7 * HID + 2 * jp);
        acc.x += bf2f(u0 & 0xFFFFu) + bf2f(u1 & 0xFFFFu)
               + bf2f(u2 & 0xFFFFu) + bf2f(u3 & 0xFFFFu)
               + bf2f(u4 & 0xFFFFu) + bf2f(u5 & 0xFFFFu)
               + bf2f(u6 & 0xFFFFu) + bf2f(u7 & 0xFFFFu);
        acc.y += bf2f(u0 >> 16) + bf2f(u1 >> 16) + bf2f(u2 >> 16) + bf2f(u3 >> 16)
               + bf2f(u4 >> 16) + bf2f(u5 >> 16) + bf2f(u6 >> 16) + bf2f(u7 >> 16);
    }
    for (; e + 2 <= end; e += 2) {
        unsigned s0 = csr[e], s1 = csr[e + 1];
        unsigned u0 = *(const unsigned*)(p2b + (size_t)s0 * HID + 2 * jp);
        unsigned u1 = *(const unsigned*)(p2b + (size_t)s1 * HID + 2 * jp);
        acc.x += bf2f(u0 & 0xFFFFu) + bf2f(u1 & 0xFFFFu);
        acc.y += bf2f(u0 >> 16) + bf2f(u1 >> 16);
    }
    for (; e < end; ++e) {
        unsigned u = *(const unsigned*)(p2b + (size_t)csr[e] * HID + 2 * jp);
        acc.x += bf2f(u & 0xFFFFu);
        acc.y += bf2f(u >> 16);
    }
    unsigned qu = *(const unsigned*)(q2b + (size_t)n * HID + 2 * jp);
    float ox = acc.x + bf2f(qu & 0xFFFFu) + sb[2 * jp];
    float oy = acc.y + bf2f(qu >> 16) + sb[2 * jp + 1];

    float m = fmaxf(ox, oy);
#pragma unroll
    for (int mask = 1; mask < 8; mask <<= 1) m = fmaxf(m, __shfl_xor(m, mask, 8));
    float s = __expf(ox - m) + __expf(oy - m);
#pragma unroll
    for (int mask = 1; mask < 8; mask <<= 1) s += __shfl_xor(s, mask, 8);
    const float l = m + __logf(s);

    if (bf) ((unsigned*)out)[(size_t)n * 8 + jp] = pack2(ox - l, oy - l);
    else    ((float2*)out)[(size_t)n * 8 + jp] = make_float2(ox - l, oy - l);
}

extern "C" void kernel_launch(void* const* d_in, const int* in_sizes, int n_in,
                              void* d_out, int out_size, void* d_ws, size_t ws_size,
                              hipStream_t stream) {
    const void* x       = d_in[0];
    const int*  ei      = (const int*)d_in[1];
    const void* w1_rel  = d_in[2];
    const void* w1_root = d_in[3];
    const void* b1      = d_in[4];
    const void* w2_rel  = d_in[5];
    const void* w2_root = d_in[6];
    const void* b2      = d_in[7];

    const int N = in_sizes[0] / DFEAT;                       // 100000
    const int E = in_sizes[1] / 2;                           // 1600000
    const int nbkt = (N + BKT_NODES - 1) / BKT_NODES;        // 782

    unsigned short* p1b = (unsigned short*)d_ws;
    unsigned short* q1b = p1b + (size_t)N * HID;
    unsigned short* p2b = q1b + (size_t)N * HID;
    unsigned short* q2b = p2b + (size_t)N * HID;
    unsigned* eb   = (unsigned*)(q2b + (size_t)N * HID);     // nbkt*CAP u32
    unsigned* csr  = eb + (size_t)nbkt * CAP;                // nbkt*CAP u32
    int* offsets   = (int*)(csr + (size_t)nbkt * CAP);       // N
    int* ends      = offsets + N;                            // N
    int* gcur      = ends + N;                               // nbkt
    int* flags     = gcur + nbkt;                            // 2

    const int nPart = (E + CHUNK - 1) / CHUNK;               // 196
    const int nLin  = (N + 127) / 128;                       // 782

    k_detect<<<1, 512, 0, stream>>>((const unsigned short*)x, ei, flags, gcur, nbkt);
    k_pl<<<nPart + nLin, 512, 0, stream>>>(ei, eb, gcur, x, w1_rel, w1_root,
                                           p1b, q1b, flags, E, nbkt, N, nPart);
    k_sagg1<<<nbkt, 512, 0, stream>>>(eb, gcur, p1b, q1b, b1, w2_rel, w2_root,
                                      p2b, q2b, csr, offsets, ends, flags, N);
    k_agg2<<<(N + 31) / 32, 256, 0, stream>>>(offsets, ends, csr, p2b, q2b, b2,
                                              d_out, flags, N);
}

// Round 6
// 155.165 us; speedup vs baseline: 2.2374x; 1.0214x over previous
//
#include <hip/hip_runtime.h>

#define DFEAT 128
#define HID 16
#define BKT_NODES 128      // dst nodes per bucket -> nbkt=782
#define BKT_SHIFT 7
#define CAP 2432           // mean 2048 + ~8.5 sigma
#define CAPI 5             // ceil(CAP/512) register-cache iterations
#define CHUNK 8192         // edges per partition block -> 196 blocks
#define NOEDGE 0xFFFFFFFFu

typedef __attribute__((ext_vector_type(8))) short short8;
typedef __attribute__((ext_vector_type(4))) float floatx4;

__device__ __forceinline__ float bf2f(unsigned v) { return __uint_as_float(v << 16); }
__device__ __forceinline__ unsigned short f2bf(float f) {
    unsigned u = __float_as_uint(f);
    return (unsigned short)((u + 0x7FFFu + ((u >> 16) & 1u)) >> 16);
}
__device__ __forceinline__ unsigned pack2(float a, float b) {
    return (unsigned)f2bf(a) | ((unsigned)f2bf(b) << 16);
}

// flags[0]=1 if float tensors are bf16; flags[1]=1 if edge_index is int64.
// Also zeros gcur (kernel, not hipMemsetAsync — graph-capture safe).
__global__ __launch_bounds__(512) void k_detect(const unsigned short* __restrict__ x,
                                                const int* __restrict__ ei,
                                                int* __restrict__ flags,
                                                int* __restrict__ gcur, int nbkt) {
    const int t = threadIdx.x;
    for (int i = t; i < nbkt; i += 512) gcur[i] = 0;
    if (t < 64) {
        unsigned short v = x[2 * t];
        int e = (v >> 7) & 0xFF;
        bool okbf = (v == 0) || (e >= 110 && e <= 130);
        unsigned long long mbf = __ballot(okbf);
        bool z = (ei[2 * t + 1] == 0);
        unsigned long long mz = __ballot(z);
        if (t == 0) {
            flags[0] = (__popcll(mbf) >= 52) ? 1 : 0;
            flags[1] = (__popcll(mz) >= 60) ? 1 : 0;
        }
    }
}

// FUSED: edge partition (blocks [0, nPart)) + layer-1 projection (rest).
// Partition now does a SINGLE LDS-atomic pass: phase-1's atomicAdd return
// value IS the block-local rank (round-5 discarded it and re-atomic'd in
// phase 3). rank<=8191 (13b) + bucket<=781 (10b) pack into one u32 ->
// zero extra VGPRs. Phase 3 is pure reads: pos = base[b] + rank.
__global__ __launch_bounds__(512) void k_pl(const int* __restrict__ ei,
                                            unsigned* __restrict__ eb,
                                            int* __restrict__ gcur,
                                            const void* __restrict__ xv,
                                            const void* __restrict__ wrel,
                                            const void* __restrict__ wroot,
                                            unsigned short* __restrict__ p1b,
                                            unsigned short* __restrict__ q1b,
                                            const int* __restrict__ flags,
                                            int E, int nbkt, int N, int nPart) {
    __shared__ int hist[1024];         // counts, then per-block global bases
    const int t = threadIdx.x;

    if ((int)blockIdx.x < nPart) {
        // ---------------- edge partition path ----------------
        for (int i = t; i < nbkt; i += 512) hist[i] = 0;
        __syncthreads();
        const int base = blockIdx.x * CHUNK;
        const int i64 = flags[1];
        unsigned pk[16];
        unsigned bkrk[16];             // (bucket<<13) | rank
        if (i64 && !(E & 1)) {
            // int64 path: one dwordx4 per edge-pair for src and dst each.
#pragma unroll
            for (int ip = 0; ip < 8; ++ip) {
                int e = base + ip * 1024 + 2 * t;
                if (e < E) {   // E even, e even -> e+1 < E too
                    int4 sv = *(const int4*)(ei + 2 * (size_t)e);
                    int4 dv = *(const int4*)(ei + 2 * ((size_t)E + e));
                    int b0 = dv.x >> BKT_SHIFT;
                    pk[2 * ip] = ((unsigned)sv.x << BKT_SHIFT) | (unsigned)(dv.x & (BKT_NODES - 1));
                    int r0 = atomicAdd(&hist[b0], 1);
                    bkrk[2 * ip] = ((unsigned)b0 << 13) | (unsigned)r0;
                    int b1 = dv.z >> BKT_SHIFT;
                    pk[2 * ip + 1] = ((unsigned)sv.z << BKT_SHIFT) | (unsigned)(dv.z & (BKT_NODES - 1));
                    int r1 = atomicAdd(&hist[b1], 1);
                    bkrk[2 * ip + 1] = ((unsigned)b1 << 13) | (unsigned)r1;
                } else {
                    bkrk[2 * ip] = NOEDGE;
                    bkrk[2 * ip + 1] = NOEDGE;
                }
            }
        } else {
#pragma unroll
            for (int i = 0; i < 16; ++i) {
                int e = base + i * 512 + t;
                if (e < E) {
                    int src, dst;
                    if (i64) { src = ei[2 * (size_t)e]; dst = ei[2 * ((size_t)E + e)]; }
                    else     { src = ei[e];             dst = ei[(size_t)E + e]; }
                    int b = dst >> BKT_SHIFT;
                    pk[i] = ((unsigned)src << BKT_SHIFT) | (unsigned)(dst & (BKT_NODES - 1));
                    int r = atomicAdd(&hist[b], 1);
                    bkrk[i] = ((unsigned)b << 13) | (unsigned)r;
                } else {
                    bkrk[i] = NOEDGE;
                }
            }
        }
        __syncthreads();
        for (int b = t; b < nbkt; b += 512) {
            int c = hist[b];
            hist[b] = c ? atomicAdd(&gcur[b], c) : 0;   // count -> global base
        }
        __syncthreads();
#pragma unroll
        for (int i = 0; i < 16; ++i) {
            if (bkrk[i] != NOEDGE) {
                int b = (int)(bkrk[i] >> 13);
                int pos = hist[b] + (int)(bkrk[i] & 0x1FFFu);
                if (pos < CAP)
                    eb[(size_t)b * CAP + pos] = pk[i];
            }
        }
        return;
    }

    // ---------------- layer-1 projection path ----------------
    // p1b = bf16(x @ w1_rel), q1b = bf16(x @ w1_root); 16 nodes/wave,
    // 8 waves -> 128 nodes per block.
    const int lane = t & 63, wave = t >> 6;
    const int bf = flags[0];
    const int m = lane & 15;
    const int quad = lane >> 4;
    const int nodebase = ((int)blockIdx.x - nPart) * 128 + wave * 16;

    short8 Brel[4], Broot[4];
    if (bf) {
        const unsigned short* a = (const unsigned short*)wrel;
        const unsigned short* c = (const unsigned short*)wroot;
#pragma unroll
        for (int kb = 0; kb < 4; ++kb) {
            short8 br, bo;
#pragma unroll
            for (int j = 0; j < 8; ++j) {
                int k = kb * 32 + quad * 8 + j;
                br[j] = (short)a[k * HID + m];
                bo[j] = (short)c[k * HID + m];
            }
            Brel[kb] = br; Broot[kb] = bo;
        }
    } else {
        const float* a = (const float*)wrel;
        const float* c = (const float*)wroot;
#pragma unroll
        for (int kb = 0; kb < 4; ++kb) {
            short8 br, bo;
#pragma unroll
            for (int j = 0; j < 8; ++j) {
                int k = kb * 32 + quad * 8 + j;
                br[j] = (short)f2bf(a[k * HID + m]);
                bo[j] = (short)f2bf(c[k * HID + m]);
            }
            Brel[kb] = br; Broot[kb] = bo;
        }
    }

    int row = nodebase + m;
    if (row >= N) row = N - 1;

    floatx4 accP = {0.f, 0.f, 0.f, 0.f}, accQ = {0.f, 0.f, 0.f, 0.f};
    if (bf) {
        const unsigned short* xp = (const unsigned short*)xv;
        const unsigned short* rp = xp + (size_t)row * DFEAT + quad * 8;
#pragma unroll
        for (int kb = 0; kb < 4; ++kb) {
            short8 A = *(const short8*)(rp + kb * 32);
            accP = __builtin_amdgcn_mfma_f32_16x16x32_bf16(A, Brel[kb], accP, 0, 0, 0);
            accQ = __builtin_amdgcn_mfma_f32_16x16x32_bf16(A, Broot[kb], accQ, 0, 0, 0);
        }
    } else {
        const float* xp = (const float*)xv;
        const float* rp = xp + (size_t)row * DFEAT + quad * 8;
#pragma unroll
        for (int kb = 0; kb < 4; ++kb) {
            float4 v0 = *(const float4*)(rp + kb * 32);
            float4 v1 = *(const float4*)(rp + kb * 32 + 4);
            short8 A;
            A[0] = (short)f2bf(v0.x); A[1] = (short)f2bf(v0.y);
            A[2] = (short)f2bf(v0.z); A[3] = (short)f2bf(v0.w);
            A[4] = (short)f2bf(v1.x); A[5] = (short)f2bf(v1.y);
            A[6] = (short)f2bf(v1.z); A[7] = (short)f2bf(v1.w);
            accP = __builtin_amdgcn_mfma_f32_16x16x32_bf16(A, Brel[kb], accP, 0, 0, 0);
            accQ = __builtin_amdgcn_mfma_f32_16x16x32_bf16(A, Broot[kb], accQ, 0, 0, 0);
        }
    }

#pragma unroll
    for (int r = 0; r < 4; ++r) {
        int node = nodebase + quad * 4 + r;
        if (node < N) {
            p1b[(size_t)node * HID + m] = f2bf(accP[r]);
            q1b[(size_t)node * HID + m] = f2bf(accQ[r]);
        }
    }
}

// Fused counting-sort + layer-1 aggregate + epilogue; one 512-thread block
// per 128-node bucket (782 blocks ~24 waves/CU). csr/offsets published
// for k_agg2 (ends derived there from offsets[gn+1] — array dropped).
__global__ __launch_bounds__(512) void k_sagg1(const unsigned* __restrict__ eb,
                                               const int* __restrict__ gcur,
                                               const unsigned short* __restrict__ p1b,
                                               const unsigned short* __restrict__ q1b,
                                               const void* __restrict__ b1,
                                               const void* __restrict__ w2rel,
                                               const void* __restrict__ w2root,
                                               unsigned short* __restrict__ p2b,
                                               unsigned short* __restrict__ q2b,
                                               unsigned* __restrict__ csr,
                                               int* __restrict__ offsets,
                                               const int* __restrict__ flags,
                                               int N) {
    __shared__ unsigned srt[CAP];       // 9.7 KB
    __shared__ int cnts[BKT_NODES];
    __shared__ int offs[BKT_NODES];
    __shared__ float4 swp[HID][8];      // {rel_j0, rel_j1, root_j0, root_j1}
    __shared__ float sb[HID];
    const int t = threadIdx.x;
    const int b = blockIdx.x;
    const int bf = flags[0];

    if (t < 128) {
        int k = t >> 3, p = t & 7;
        float4 w;
        if (bf) {
            const unsigned short* a = (const unsigned short*)w2rel;
            const unsigned short* c = (const unsigned short*)w2root;
            w = make_float4(bf2f(a[k * 16 + 2 * p]), bf2f(a[k * 16 + 2 * p + 1]),
                            bf2f(c[k * 16 + 2 * p]), bf2f(c[k * 16 + 2 * p + 1]));
        } else {
            const float* a = (const float*)w2rel;
            const float* c = (const float*)w2root;
            w = make_float4(a[k * 16 + 2 * p], a[k * 16 + 2 * p + 1],
                            c[k * 16 + 2 * p], c[k * 16 + 2 * p + 1]);
        }
        swp[k][p] = w;
    }
    if (t < HID) sb[t] = bf ? bf2f(((const unsigned short*)b1)[t]) : ((const float*)b1)[t];
    if (t < BKT_NODES) cnts[t] = 0;
    __syncthreads();

    int cnt = gcur[b];
    if (cnt < 0) cnt = 0;
    if (cnt > CAP) cnt = CAP;
    const unsigned* ep = eb + (size_t)b * CAP;

    unsigned ev[CAPI];
    int rk[CAPI];
#pragma unroll
    for (int i = 0; i < CAPI; ++i) {
        int e = i * 512 + t;
        if (e < cnt) {
            unsigned w = ep[e];
            ev[i] = w;
            rk[i] = atomicAdd(&cnts[w & (BKT_NODES - 1u)], 1);
        } else ev[i] = NOEDGE;
    }
    __syncthreads();
    // inclusive scan of counts (threads [0,128) active; barriers uniform)
    if (t < BKT_NODES) offs[t] = cnts[t];
    __syncthreads();
    for (int off = 1; off < BKT_NODES; off <<= 1) {
        int v = 0;
        if (t >= off && t < BKT_NODES) v = offs[t - off];
        __syncthreads();
        if (t < BKT_NODES) offs[t] += v;
        __syncthreads();
    }
#pragma unroll
    for (int i = 0; i < CAPI; ++i) {
        if (ev[i] != NOEDGE) {
            unsigned local = ev[i] & (BKT_NODES - 1u);
            int pos = offs[local] - cnts[local] + rk[i];   // exclusive + rank
            srt[pos] = ev[i] >> BKT_SHIFT;
        }
    }
    __syncthreads();

    // publish CSR for k_agg2 (fixed-stride base, coalesced)
    const int base = b * CAP;
    for (int e = t; e < cnt; e += 512) csr[base + e] = srt[e];
    const int gb = b * BKT_NODES;
    if (t < BKT_NODES) {
        int gn = gb + t;
        if (gn < N) offsets[gn] = base + offs[t] - cnts[t];
    }

    // layer-1 aggregate from LDS srt + fused relu/bias/matmuls.
    const int grp = t >> 3, jp = t & 7;   // 64 groups; 128 nodes -> 2 per group
#pragma unroll
    for (int g = 0; g < 2; ++g) {
        int node = g * 64 + grp;
        int gn = gb + node;
        int beg = offs[node] - cnts[node];
        int end = offs[node];
        float2 acc = make_float2(0.f, 0.f);
        int e = beg;
        for (; e + 4 <= end; e += 4) {
            unsigned s0 = srt[e], s1 = srt[e + 1], s2 = srt[e + 2], s3 = srt[e + 3];
            unsigned u0 = *(const unsigned*)(p1b + (size_t)s0 * HID + 2 * jp);
            unsigned u1 = *(const unsigned*)(p1b + (size_t)s1 * HID + 2 * jp);
            unsigned u2 = *(const unsigned*)(p1b + (size_t)s2 * HID + 2 * jp);
            unsigned u3 = *(const unsigned*)(p1b + (size_t)s3 * HID + 2 * jp);
            acc.x += bf2f(u0 & 0xFFFFu) + bf2f(u1 & 0xFFFFu)
                   + bf2f(u2 & 0xFFFFu) + bf2f(u3 & 0xFFFFu);
            acc.y += bf2f(u0 >> 16) + bf2f(u1 >> 16) + bf2f(u2 >> 16) + bf2f(u3 >> 16);
        }
        for (; e < end; ++e) {
            unsigned u = *(const unsigned*)(p1b + (size_t)srt[e] * HID + 2 * jp);
            acc.x += bf2f(u & 0xFFFFu);
            acc.y += bf2f(u >> 16);
        }
        float hx = 0.f, hy = 0.f;
        if (gn < N) {
            unsigned qu = *(const unsigned*)(q1b + (size_t)gn * HID + 2 * jp);
            hx = fmaxf(acc.x + bf2f(qu & 0xFFFFu) + sb[2 * jp], 0.f);
            hy = fmaxf(acc.y + bf2f(qu >> 16) + sb[2 * jp + 1], 0.f);
        }
        float2 sp = make_float2(0.f, 0.f), sq = make_float2(0.f, 0.f);
#pragma unroll
        for (int k = 0; k < HID; ++k) {
            float hsel = (k & 1) ? hy : hx;
            float hk = __shfl(hsel, k >> 1, 8);
            float4 w = swp[k][jp];
            sp.x += hk * w.x; sp.y += hk * w.y;
            sq.x += hk * w.z; sq.y += hk * w.w;
        }
        if (gn < N) {
            ((unsigned*)p2b)[(size_t)gn * 8 + jp] = pack2(sp.x, sp.y);
            ((unsigned*)q2b)[(size_t)gn * 8 + jp] = pack2(sq.x, sq.y);
        }
    }
}

// Layer 2 aggregate, bucket-block version: one 512-thread block per bucket,
// coalesced csr segment load into LDS, index reads from LDS (broadcast),
// only the p2b gather goes to L2. log_softmax epilogue.
__global__ __launch_bounds__(512) void k_agg2(const int* __restrict__ offsets,
                                              const int* __restrict__ gcur,
                                              const unsigned* __restrict__ csr,
                                              const unsigned short* __restrict__ p2b,
                                              const unsigned short* __restrict__ q2b,
                                              const void* __restrict__ b2,
                                              void* __restrict__ out,
                                              const int* __restrict__ flags,
                                              int N) {
    __shared__ unsigned srt[CAP];       // 9.7 KB
    __shared__ float sb[HID];
    const int t = threadIdx.x;
    const int b = blockIdx.x;
    const int bf = flags[0];
    if (t < HID) sb[t] = bf ? bf2f(((const unsigned short*)b2)[t]) : ((const float*)b2)[t];

    int cnt = gcur[b];
    if (cnt < 0) cnt = 0;
    if (cnt > CAP) cnt = CAP;
    const int base = b * CAP;
    for (int e = t; e < cnt; e += 512) srt[e] = csr[base + e];
    __syncthreads();

    const int gb = b * BKT_NODES;
    const int grp = t >> 3, jp = t & 7;   // 64 groups; 128 nodes -> 2 per group
#pragma unroll
    for (int g = 0; g < 2; ++g) {
        int node = g * 64 + grp;
        int gn = gb + node;
        int beg = 0, end = 0;
        if (gn < N) {
            beg = offsets[gn] - base;
            end = (node == BKT_NODES - 1 || gn + 1 >= N) ? cnt : offsets[gn + 1] - base;
        }
        float2 acc = make_float2(0.f, 0.f);
        int e = beg;
        for (; e + 8 <= end; e += 8) {
            unsigned s0 = srt[e],     s1 = srt[e + 1], s2 = srt[e + 2], s3 = srt[e + 3];
            unsigned s4 = srt[e + 4], s5 = srt[e + 5], s6 = srt[e + 6], s7 = srt[e + 7];
            unsigned u0 = *(const unsigned*)(p2b + (size_t)s0 * HID + 2 * jp);
            unsigned u1 = *(const unsigned*)(p2b + (size_t)s1 * HID + 2 * jp);
            unsigned u2 = *(const unsigned*)(p2b + (size_t)s2 * HID + 2 * jp);
            unsigned u3 = *(const unsigned*)(p2b + (size_t)s3 * HID + 2 * jp);
            unsigned u4 = *(const unsigned*)(p2b + (size_t)s4 * HID + 2 * jp);
            unsigned u5 = *(const unsigned*)(p2b + (size_t)s5 * HID + 2 * jp);
            unsigned u6 = *(const unsigned*)(p2b + (size_t)s6 * HID + 2 * jp);
            unsigned u7 = *(const unsigned*)(p2b + (size_t)s7 * HID + 2 * jp);
            acc.x += bf2f(u0 & 0xFFFFu) + bf2f(u1 & 0xFFFFu)
                   + bf2f(u2 & 0xFFFFu) + bf2f(u3 & 0xFFFFu)
                   + bf2f(u4 & 0xFFFFu) + bf2f(u5 & 0xFFFFu)
                   + bf2f(u6 & 0xFFFFu) + bf2f(u7 & 0xFFFFu);
            acc.y += bf2f(u0 >> 16) + bf2f(u1 >> 16) + bf2f(u2 >> 16) + bf2f(u3 >> 16)
                   + bf2f(u4 >> 16) + bf2f(u5 >> 16) + bf2f(u6 >> 16) + bf2f(u7 >> 16);
        }
        for (; e + 2 <= end; e += 2) {
            unsigned s0 = srt[e], s1 = srt[e + 1];
            unsigned u0 = *(const unsigned*)(p2b + (size_t)s0 * HID + 2 * jp);
            unsigned u1 = *(const unsigned*)(p2b + (size_t)s1 * HID + 2 * jp);
            acc.x += bf2f(u0 & 0xFFFFu) + bf2f(u1 & 0xFFFFu);
            acc.y += bf2f(u0 >> 16) + bf2f(u1 >> 16);
        }
        for (; e < end; ++e) {
            unsigned u = *(const unsigned*)(p2b + (size_t)srt[e] * HID + 2 * jp);
            acc.x += bf2f(u & 0xFFFFu);
            acc.y += bf2f(u >> 16);
        }
        float ox = 0.f, oy = 0.f;
        if (gn < N) {
            unsigned qu = *(const unsigned*)(q2b + (size_t)gn * HID + 2 * jp);
            ox = acc.x + bf2f(qu & 0xFFFFu) + sb[2 * jp];
            oy = acc.y + bf2f(qu >> 16) + sb[2 * jp + 1];
        }
        float m = fmaxf(ox, oy);
#pragma unroll
        for (int mask = 1; mask < 8; mask <<= 1) m = fmaxf(m, __shfl_xor(m, mask, 8));
        float s = __expf(ox - m) + __expf(oy - m);
#pragma unroll
        for (int mask = 1; mask < 8; mask <<= 1) s += __shfl_xor(s, mask, 8);
        const float l = m + __logf(s);
        if (gn < N) {
            if (bf) ((unsigned*)out)[(size_t)gn * 8 + jp] = pack2(ox - l, oy - l);
            else    ((float2*)out)[(size_t)gn * 8 + jp] = make_float2(ox - l, oy - l);
        }
    }
}

extern "C" void kernel_launch(void* const* d_in, const int* in_sizes, int n_in,
                              void* d_out, int out_size, void* d_ws, size_t ws_size,
                              hipStream_t stream) {
    const void* x       = d_in[0];
    const int*  ei      = (const int*)d_in[1];
    const void* w1_rel  = d_in[2];
    const void* w1_root = d_in[3];
    const void* b1      = d_in[4];
    const void* w2_rel  = d_in[5];
    const void* w2_root = d_in[6];
    const void* b2      = d_in[7];

    const int N = in_sizes[0] / DFEAT;                       // 100000
    const int E = in_sizes[1] / 2;                           // 1600000
    const int nbkt = (N + BKT_NODES - 1) / BKT_NODES;        // 782

    unsigned short* p1b = (unsigned short*)d_ws;
    unsigned short* q1b = p1b + (size_t)N * HID;
    unsigned short* p2b = q1b + (size_t)N * HID;
    unsigned short* q2b = p2b + (size_t)N * HID;
    unsigned* eb   = (unsigned*)(q2b + (size_t)N * HID);     // nbkt*CAP u32
    unsigned* csr  = eb + (size_t)nbkt * CAP;                // nbkt*CAP u32
    int* offsets   = (int*)(csr + (size_t)nbkt * CAP);       // N
    int* gcur      = offsets + N;                            // nbkt
    int* flags     = gcur + nbkt;                            // 2

    const int nPart = (E + CHUNK - 1) / CHUNK;               // 196
    const int nLin  = (N + 127) / 128;                       // 782

    k_detect<<<1, 512, 0, stream>>>((const unsigned short*)x, ei, flags, gcur, nbkt);
    k_pl<<<nPart + nLin, 512, 0, stream>>>(ei, eb, gcur, x, w1_rel, w1_root,
                                           p1b, q1b, flags, E, nbkt, N, nPart);
    k_sagg1<<<nbkt, 512, 0, stream>>>(eb, gcur, p1b, q1b, b1, w2_rel, w2_root,
                                      p2b, q2b, csr, offsets, flags, N);
    k_agg2<<<nbkt, 512, 0, stream>>>(offsets, gcur, csr, p2b, q2b, b2,
                                     d_out, flags, N);
}

// Round 7
// 154.381 us; speedup vs baseline: 2.2487x; 1.0051x over previous
//
#include <hip/hip_runtime.h>

#define DFEAT 128
#define HID 16
#define BKT_NODES 128      // dst nodes per bucket -> nbkt=782
#define BKT_SHIFT 7
#define CAP 2432           // mean 2048 + ~8.5 sigma
#define CAPI 5             // ceil(CAP/512) register-cache iterations
#define CHUNK 8192         // edges per partition block -> 196 blocks
#define NOEDGE 0xFFFFFFFFu

typedef __attribute__((ext_vector_type(8))) short short8;
typedef __attribute__((ext_vector_type(4))) float floatx4;

__device__ __forceinline__ float bf2f(unsigned v) { return __uint_as_float(v << 16); }
__device__ __forceinline__ unsigned short f2bf(float f) {
    unsigned u = __float_as_uint(f);
    return (unsigned short)((u + 0x7FFFu + ((u >> 16) & 1u)) >> 16);
}
__device__ __forceinline__ unsigned pack2(float a, float b) {
    return (unsigned)f2bf(a) | ((unsigned)f2bf(b) << 16);
}

// flags[0]=1 if float tensors are bf16; flags[1]=1 if edge_index is int64.
// Also zeros gcur (kernel, not hipMemsetAsync — graph-capture safe).
__global__ __launch_bounds__(512) void k_detect(const unsigned short* __restrict__ x,
                                                const int* __restrict__ ei,
                                                int* __restrict__ flags,
                                                int* __restrict__ gcur, int nbkt) {
    const int t = threadIdx.x;
    for (int i = t; i < nbkt; i += 512) gcur[i] = 0;
    if (t < 64) {
        unsigned short v = x[2 * t];
        int e = (v >> 7) & 0xFF;
        bool okbf = (v == 0) || (e >= 110 && e <= 130);
        unsigned long long mbf = __ballot(okbf);
        bool z = (ei[2 * t + 1] == 0);
        unsigned long long mz = __ballot(z);
        if (t == 0) {
            flags[0] = (__popcll(mbf) >= 52) ? 1 : 0;
            flags[1] = (__popcll(mz) >= 60) ? 1 : 0;
        }
    }
}

// FUSED: edge partition (blocks [0, nPart)) + layer-1 projection (rest).
// Partition: single LDS-atomic pass; rank packed (bucket<<13)|rank.
__global__ __launch_bounds__(512) void k_pl(const int* __restrict__ ei,
                                            unsigned* __restrict__ eb,
                                            int* __restrict__ gcur,
                                            const void* __restrict__ xv,
                                            const void* __restrict__ wrel,
                                            const void* __restrict__ wroot,
                                            unsigned short* __restrict__ p1b,
                                            unsigned short* __restrict__ q1b,
                                            const int* __restrict__ flags,
                                            int E, int nbkt, int N, int nPart) {
    __shared__ int hist[1024];         // counts, then per-block global bases
    const int t = threadIdx.x;

    if ((int)blockIdx.x < nPart) {
        // ---------------- edge partition path ----------------
        for (int i = t; i < nbkt; i += 512) hist[i] = 0;
        __syncthreads();
        const int base = blockIdx.x * CHUNK;
        const int i64 = flags[1];
        unsigned pk[16];
        unsigned bkrk[16];             // (bucket<<13) | rank
        if (i64 && !(E & 1)) {
            // int64 path: one dwordx4 per edge-pair for src and dst each.
#pragma unroll
            for (int ip = 0; ip < 8; ++ip) {
                int e = base + ip * 1024 + 2 * t;
                if (e < E) {   // E even, e even -> e+1 < E too
                    int4 sv = *(const int4*)(ei + 2 * (size_t)e);
                    int4 dv = *(const int4*)(ei + 2 * ((size_t)E + e));
                    int b0 = dv.x >> BKT_SHIFT;
                    pk[2 * ip] = ((unsigned)sv.x << BKT_SHIFT) | (unsigned)(dv.x & (BKT_NODES - 1));
                    int r0 = atomicAdd(&hist[b0], 1);
                    bkrk[2 * ip] = ((unsigned)b0 << 13) | (unsigned)r0;
                    int b1 = dv.z >> BKT_SHIFT;
                    pk[2 * ip + 1] = ((unsigned)sv.z << BKT_SHIFT) | (unsigned)(dv.z & (BKT_NODES - 1));
                    int r1 = atomicAdd(&hist[b1], 1);
                    bkrk[2 * ip + 1] = ((unsigned)b1 << 13) | (unsigned)r1;
                } else {
                    bkrk[2 * ip] = NOEDGE;
                    bkrk[2 * ip + 1] = NOEDGE;
                }
            }
        } else {
#pragma unroll
            for (int i = 0; i < 16; ++i) {
                int e = base + i * 512 + t;
                if (e < E) {
                    int src, dst;
                    if (i64) { src = ei[2 * (size_t)e]; dst = ei[2 * ((size_t)E + e)]; }
                    else     { src = ei[e];             dst = ei[(size_t)E + e]; }
                    int b = dst >> BKT_SHIFT;
                    pk[i] = ((unsigned)src << BKT_SHIFT) | (unsigned)(dst & (BKT_NODES - 1));
                    int r = atomicAdd(&hist[b], 1);
                    bkrk[i] = ((unsigned)b << 13) | (unsigned)r;
                } else {
                    bkrk[i] = NOEDGE;
                }
            }
        }
        __syncthreads();
        for (int b = t; b < nbkt; b += 512) {
            int c = hist[b];
            hist[b] = c ? atomicAdd(&gcur[b], c) : 0;   // count -> global base
        }
        __syncthreads();
#pragma unroll
        for (int i = 0; i < 16; ++i) {
            if (bkrk[i] != NOEDGE) {
                int b = (int)(bkrk[i] >> 13);
                int pos = hist[b] + (int)(bkrk[i] & 0x1FFFu);
                if (pos < CAP)
                    eb[(size_t)b * CAP + pos] = pk[i];
            }
        }
        return;
    }

    // ---------------- layer-1 projection path ----------------
    const int lane = t & 63, wave = t >> 6;
    const int bf = flags[0];
    const int m = lane & 15;
    const int quad = lane >> 4;
    const int nodebase = ((int)blockIdx.x - nPart) * 128 + wave * 16;

    short8 Brel[4], Broot[4];
    if (bf) {
        const unsigned short* a = (const unsigned short*)wrel;
        const unsigned short* c = (const unsigned short*)wroot;
#pragma unroll
        for (int kb = 0; kb < 4; ++kb) {
            short8 br, bo;
#pragma unroll
            for (int j = 0; j < 8; ++j) {
                int k = kb * 32 + quad * 8 + j;
                br[j] = (short)a[k * HID + m];
                bo[j] = (short)c[k * HID + m];
            }
            Brel[kb] = br; Broot[kb] = bo;
        }
    } else {
        const float* a = (const float*)wrel;
        const float* c = (const float*)wroot;
#pragma unroll
        for (int kb = 0; kb < 4; ++kb) {
            short8 br, bo;
#pragma unroll
            for (int j = 0; j < 8; ++j) {
                int k = kb * 32 + quad * 8 + j;
                br[j] = (short)f2bf(a[k * HID + m]);
                bo[j] = (short)f2bf(c[k * HID + m]);
            }
            Brel[kb] = br; Broot[kb] = bo;
        }
    }

    int row = nodebase + m;
    if (row >= N) row = N - 1;

    floatx4 accP = {0.f, 0.f, 0.f, 0.f}, accQ = {0.f, 0.f, 0.f, 0.f};
    if (bf) {
        const unsigned short* xp = (const unsigned short*)xv;
        const unsigned short* rp = xp + (size_t)row * DFEAT + quad * 8;
#pragma unroll
        for (int kb = 0; kb < 4; ++kb) {
            short8 A = *(const short8*)(rp + kb * 32);
            accP = __builtin_amdgcn_mfma_f32_16x16x32_bf16(A, Brel[kb], accP, 0, 0, 0);
            accQ = __builtin_amdgcn_mfma_f32_16x16x32_bf16(A, Broot[kb], accQ, 0, 0, 0);
        }
    } else {
        const float* xp = (const float*)xv;
        const float* rp = xp + (size_t)row * DFEAT + quad * 8;
#pragma unroll
        for (int kb = 0; kb < 4; ++kb) {
            float4 v0 = *(const float4*)(rp + kb * 32);
            float4 v1 = *(const float4*)(rp + kb * 32 + 4);
            short8 A;
            A[0] = (short)f2bf(v0.x); A[1] = (short)f2bf(v0.y);
            A[2] = (short)f2bf(v0.z); A[3] = (short)f2bf(v0.w);
            A[4] = (short)f2bf(v1.x); A[5] = (short)f2bf(v1.y);
            A[6] = (short)f2bf(v1.z); A[7] = (short)f2bf(v1.w);
            accP = __builtin_amdgcn_mfma_f32_16x16x32_bf16(A, Brel[kb], accP, 0, 0, 0);
            accQ = __builtin_amdgcn_mfma_f32_16x16x32_bf16(A, Broot[kb], accQ, 0, 0, 0);
        }
    }

#pragma unroll
    for (int r = 0; r < 4; ++r) {
        int node = nodebase + quad * 4 + r;
        if (node < N) {
            p1b[(size_t)node * HID + m] = f2bf(accP[r]);
            q1b[(size_t)node * HID + m] = f2bf(accQ[r]);
        }
    }
}

// Fused counting-sort + layer-1 aggregate + epilogue; one 512-thread block
// per 128-node bucket. GATHER LAYOUT CHANGE (round 7): 4 lanes/node x 8B
// uint2 loads (was 8 lanes x 4B) — halves load instrs/edge, doubles nodes
// walked per wave (8->16), 512 threads = exactly 128 nodes (no g loop).
__global__ __launch_bounds__(512) void k_sagg1(const unsigned* __restrict__ eb,
                                               const int* __restrict__ gcur,
                                               const unsigned short* __restrict__ p1b,
                                               const unsigned short* __restrict__ q1b,
                                               const void* __restrict__ b1,
                                               const void* __restrict__ w2rel,
                                               const void* __restrict__ w2root,
                                               unsigned short* __restrict__ p2b,
                                               unsigned short* __restrict__ q2b,
                                               unsigned* __restrict__ csr,
                                               int* __restrict__ offsets,
                                               const int* __restrict__ flags,
                                               int N) {
    __shared__ unsigned srt[CAP];       // 9.7 KB
    __shared__ int cnts[BKT_NODES];
    __shared__ int offs[BKT_NODES];
    __shared__ float4 swpR[HID][4];     // w2rel[k][4jp..4jp+3]
    __shared__ float4 swpO[HID][4];     // w2root[k][4jp..4jp+3]
    __shared__ float sb[HID];
    const int t = threadIdx.x;
    const int b = blockIdx.x;
    const int bf = flags[0];

    if (t < 64) {
        int k = t >> 2, p = t & 3;
        float4 wr, wo;
        if (bf) {
            const unsigned short* a = (const unsigned short*)w2rel;
            const unsigned short* c = (const unsigned short*)w2root;
            wr = make_float4(bf2f(a[k * 16 + 4 * p]),     bf2f(a[k * 16 + 4 * p + 1]),
                             bf2f(a[k * 16 + 4 * p + 2]), bf2f(a[k * 16 + 4 * p + 3]));
            wo = make_float4(bf2f(c[k * 16 + 4 * p]),     bf2f(c[k * 16 + 4 * p + 1]),
                             bf2f(c[k * 16 + 4 * p + 2]), bf2f(c[k * 16 + 4 * p + 3]));
        } else {
            const float* a = (const float*)w2rel;
            const float* c = (const float*)w2root;
            wr = make_float4(a[k * 16 + 4 * p], a[k * 16 + 4 * p + 1],
                             a[k * 16 + 4 * p + 2], a[k * 16 + 4 * p + 3]);
            wo = make_float4(c[k * 16 + 4 * p], c[k * 16 + 4 * p + 1],
                             c[k * 16 + 4 * p + 2], c[k * 16 + 4 * p + 3]);
        }
        swpR[k][p] = wr;
        swpO[k][p] = wo;
    }
    if (t < HID) sb[t] = bf ? bf2f(((const unsigned short*)b1)[t]) : ((const float*)b1)[t];
    if (t < BKT_NODES) cnts[t] = 0;
    __syncthreads();

    int cnt = gcur[b];
    if (cnt < 0) cnt = 0;
    if (cnt > CAP) cnt = CAP;
    const unsigned* ep = eb + (size_t)b * CAP;

    unsigned ev[CAPI];
    int rk[CAPI];
#pragma unroll
    for (int i = 0; i < CAPI; ++i) {
        int e = i * 512 + t;
        if (e < cnt) {
            unsigned w = ep[e];
            ev[i] = w;
            rk[i] = atomicAdd(&cnts[w & (BKT_NODES - 1u)], 1);
        } else ev[i] = NOEDGE;
    }
    __syncthreads();
    // inclusive scan of counts (threads [0,128) active; barriers uniform)
    if (t < BKT_NODES) offs[t] = cnts[t];
    __syncthreads();
    for (int off = 1; off < BKT_NODES; off <<= 1) {
        int v = 0;
        if (t >= off && t < BKT_NODES) v = offs[t - off];
        __syncthreads();
        if (t < BKT_NODES) offs[t] += v;
        __syncthreads();
    }
#pragma unroll
    for (int i = 0; i < CAPI; ++i) {
        if (ev[i] != NOEDGE) {
            unsigned local = ev[i] & (BKT_NODES - 1u);
            int pos = offs[local] - cnts[local] + rk[i];   // exclusive + rank
            srt[pos] = ev[i] >> BKT_SHIFT;
        }
    }
    __syncthreads();

    // publish CSR for k_agg2 (fixed-stride base, coalesced)
    const int base = b * CAP;
    for (int e = t; e < cnt; e += 512) csr[base + e] = srt[e];
    const int gb = b * BKT_NODES;
    if (t < BKT_NODES) {
        int gn = gb + t;
        if (gn < N) offsets[gn] = base + offs[t] - cnts[t];
    }

    // layer-1 aggregate: 4 lanes/node, each lane owns 4 hidden dims.
    const int node = t >> 2, jp = t & 3;
    const int gn = gb + node;
    const int beg = offs[node] - cnts[node];
    const int end = offs[node];
    float a0 = 0.f, a1 = 0.f, a2 = 0.f, a3 = 0.f;
    int e = beg;
    for (; e + 8 <= end; e += 8) {
        uint2 u0 = *(const uint2*)(p1b + (size_t)srt[e + 0] * HID + 4 * jp);
        uint2 u1 = *(const uint2*)(p1b + (size_t)srt[e + 1] * HID + 4 * jp);
        uint2 u2 = *(const uint2*)(p1b + (size_t)srt[e + 2] * HID + 4 * jp);
        uint2 u3 = *(const uint2*)(p1b + (size_t)srt[e + 3] * HID + 4 * jp);
        uint2 u4 = *(const uint2*)(p1b + (size_t)srt[e + 4] * HID + 4 * jp);
        uint2 u5 = *(const uint2*)(p1b + (size_t)srt[e + 5] * HID + 4 * jp);
        uint2 u6 = *(const uint2*)(p1b + (size_t)srt[e + 6] * HID + 4 * jp);
        uint2 u7 = *(const uint2*)(p1b + (size_t)srt[e + 7] * HID + 4 * jp);
        a0 += bf2f(u0.x & 0xFFFFu) + bf2f(u1.x & 0xFFFFu) + bf2f(u2.x & 0xFFFFu) + bf2f(u3.x & 0xFFFFu)
            + bf2f(u4.x & 0xFFFFu) + bf2f(u5.x & 0xFFFFu) + bf2f(u6.x & 0xFFFFu) + bf2f(u7.x & 0xFFFFu);
        a1 += bf2f(u0.x >> 16) + bf2f(u1.x >> 16) + bf2f(u2.x >> 16) + bf2f(u3.x >> 16)
            + bf2f(u4.x >> 16) + bf2f(u5.x >> 16) + bf2f(u6.x >> 16) + bf2f(u7.x >> 16);
        a2 += bf2f(u0.y & 0xFFFFu) + bf2f(u1.y & 0xFFFFu) + bf2f(u2.y & 0xFFFFu) + bf2f(u3.y & 0xFFFFu)
            + bf2f(u4.y & 0xFFFFu) + bf2f(u5.y & 0xFFFFu) + bf2f(u6.y & 0xFFFFu) + bf2f(u7.y & 0xFFFFu);
        a3 += bf2f(u0.y >> 16) + bf2f(u1.y >> 16) + bf2f(u2.y >> 16) + bf2f(u3.y >> 16)
            + bf2f(u4.y >> 16) + bf2f(u5.y >> 16) + bf2f(u6.y >> 16) + bf2f(u7.y >> 16);
    }
    for (; e + 2 <= end; e += 2) {
        uint2 u0 = *(const uint2*)(p1b + (size_t)srt[e] * HID + 4 * jp);
        uint2 u1 = *(const uint2*)(p1b + (size_t)srt[e + 1] * HID + 4 * jp);
        a0 += bf2f(u0.x & 0xFFFFu) + bf2f(u1.x & 0xFFFFu);
        a1 += bf2f(u0.x >> 16) + bf2f(u1.x >> 16);
        a2 += bf2f(u0.y & 0xFFFFu) + bf2f(u1.y & 0xFFFFu);
        a3 += bf2f(u0.y >> 16) + bf2f(u1.y >> 16);
    }
    for (; e < end; ++e) {
        uint2 u = *(const uint2*)(p1b + (size_t)srt[e] * HID + 4 * jp);
        a0 += bf2f(u.x & 0xFFFFu);
        a1 += bf2f(u.x >> 16);
        a2 += bf2f(u.y & 0xFFFFu);
        a3 += bf2f(u.y >> 16);
    }
    float h0 = 0.f, h1 = 0.f, h2 = 0.f, h3 = 0.f;
    if (gn < N) {
        uint2 qu = *(const uint2*)(q1b + (size_t)gn * HID + 4 * jp);
        h0 = fmaxf(a0 + bf2f(qu.x & 0xFFFFu) + sb[4 * jp], 0.f);
        h1 = fmaxf(a1 + bf2f(qu.x >> 16)     + sb[4 * jp + 1], 0.f);
        h2 = fmaxf(a2 + bf2f(qu.y & 0xFFFFu) + sb[4 * jp + 2], 0.f);
        h3 = fmaxf(a3 + bf2f(qu.y >> 16)     + sb[4 * jp + 3], 0.f);
    }
    float p0 = 0.f, p1 = 0.f, p2 = 0.f, p3 = 0.f;
    float q0 = 0.f, q1 = 0.f, q2 = 0.f, q3 = 0.f;
#pragma unroll
    for (int k = 0; k < HID; ++k) {
        float hsel = ((k & 3) == 0) ? h0 : ((k & 3) == 1) ? h1 : ((k & 3) == 2) ? h2 : h3;
        float hk = __shfl(hsel, k >> 2, 4);
        float4 wr = swpR[k][jp];
        float4 wo = swpO[k][jp];
        p0 += hk * wr.x; p1 += hk * wr.y; p2 += hk * wr.z; p3 += hk * wr.w;
        q0 += hk * wo.x; q1 += hk * wo.y; q2 += hk * wo.z; q3 += hk * wo.w;
    }
    if (gn < N) {
        uint2 pv; pv.x = pack2(p0, p1); pv.y = pack2(p2, p3);
        uint2 qv; qv.x = pack2(q0, q1); qv.y = pack2(q2, q3);
        ((uint2*)p2b)[(size_t)gn * 4 + jp] = pv;
        ((uint2*)q2b)[(size_t)gn * 4 + jp] = qv;
    }
}

// Layer 2 aggregate, bucket-block version, 4 lanes/node x 8B gathers,
// log_softmax epilogue (width-4 reductions).
__global__ __launch_bounds__(512) void k_agg2(const int* __restrict__ offsets,
                                              const int* __restrict__ gcur,
                                              const unsigned* __restrict__ csr,
                                              const unsigned short* __restrict__ p2b,
                                              const unsigned short* __restrict__ q2b,
                                              const void* __restrict__ b2,
                                              void* __restrict__ out,
                                              const int* __restrict__ flags,
                                              int N) {
    __shared__ unsigned srt[CAP];       // 9.7 KB
    __shared__ float sb[HID];
    const int t = threadIdx.x;
    const int b = blockIdx.x;
    const int bf = flags[0];
    if (t < HID) sb[t] = bf ? bf2f(((const unsigned short*)b2)[t]) : ((const float*)b2)[t];

    int cnt = gcur[b];
    if (cnt < 0) cnt = 0;
    if (cnt > CAP) cnt = CAP;
    const int base = b * CAP;
    for (int e = t; e < cnt; e += 512) srt[e] = csr[base + e];
    __syncthreads();

    const int gb = b * BKT_NODES;
    const int node = t >> 2, jp = t & 3;
    const int gn = gb + node;
    int beg = 0, end = 0;
    if (gn < N) {
        beg = offsets[gn] - base;
        end = (node == BKT_NODES - 1 || gn + 1 >= N) ? cnt : offsets[gn + 1] - base;
    }
    float a0 = 0.f, a1 = 0.f, a2 = 0.f, a3 = 0.f;
    int e = beg;
    for (; e + 8 <= end; e += 8) {
        uint2 u0 = *(const uint2*)(p2b + (size_t)srt[e + 0] * HID + 4 * jp);
        uint2 u1 = *(const uint2*)(p2b + (size_t)srt[e + 1] * HID + 4 * jp);
        uint2 u2 = *(const uint2*)(p2b + (size_t)srt[e + 2] * HID + 4 * jp);
        uint2 u3 = *(const uint2*)(p2b + (size_t)srt[e + 3] * HID + 4 * jp);
        uint2 u4 = *(const uint2*)(p2b + (size_t)srt[e + 4] * HID + 4 * jp);
        uint2 u5 = *(const uint2*)(p2b + (size_t)srt[e + 5] * HID + 4 * jp);
        uint2 u6 = *(const uint2*)(p2b + (size_t)srt[e + 6] * HID + 4 * jp);
        uint2 u7 = *(const uint2*)(p2b + (size_t)srt[e + 7] * HID + 4 * jp);
        a0 += bf2f(u0.x & 0xFFFFu) + bf2f(u1.x & 0xFFFFu) + bf2f(u2.x & 0xFFFFu) + bf2f(u3.x & 0xFFFFu)
            + bf2f(u4.x & 0xFFFFu) + bf2f(u5.x & 0xFFFFu) + bf2f(u6.x & 0xFFFFu) + bf2f(u7.x & 0xFFFFu);
        a1 += bf2f(u0.x >> 16) + bf2f(u1.x >> 16) + bf2f(u2.x >> 16) + bf2f(u3.x >> 16)
            + bf2f(u4.x >> 16) + bf2f(u5.x >> 16) + bf2f(u6.x >> 16) + bf2f(u7.x >> 16);
        a2 += bf2f(u0.y & 0xFFFFu) + bf2f(u1.y & 0xFFFFu) + bf2f(u2.y & 0xFFFFu) + bf2f(u3.y & 0xFFFFu)
            + bf2f(u4.y & 0xFFFFu) + bf2f(u5.y & 0xFFFFu) + bf2f(u6.y & 0xFFFFu) + bf2f(u7.y & 0xFFFFu);
        a3 += bf2f(u0.y >> 16) + bf2f(u1.y >> 16) + bf2f(u2.y >> 16) + bf2f(u3.y >> 16)
            + bf2f(u4.y >> 16) + bf2f(u5.y >> 16) + bf2f(u6.y >> 16) + bf2f(u7.y >> 16);
    }
    for (; e + 2 <= end; e += 2) {
        uint2 u0 = *(const uint2*)(p2b + (size_t)srt[e] * HID + 4 * jp);
        uint2 u1 = *(const uint2*)(p2b + (size_t)srt[e + 1] * HID + 4 * jp);
        a0 += bf2f(u0.x & 0xFFFFu) + bf2f(u1.x & 0xFFFFu);
        a1 += bf2f(u0.x >> 16) + bf2f(u1.x >> 16);
        a2 += bf2f(u0.y & 0xFFFFu) + bf2f(u1.y & 0xFFFFu);
        a3 += bf2f(u0.y >> 16) + bf2f(u1.y >> 16);
    }
    for (; e < end; ++e) {
        uint2 u = *(const uint2*)(p2b + (size_t)srt[e] * HID + 4 * jp);
        a0 += bf2f(u.x & 0xFFFFu);
        a1 += bf2f(u.x >> 16);
        a2 += bf2f(u.y & 0xFFFFu);
        a3 += bf2f(u.y >> 16);
    }
    float o0 = 0.f, o1 = 0.f, o2 = 0.f, o3 = 0.f;
    if (gn < N) {
        uint2 qu = *(const uint2*)(q2b + (size_t)gn * HID + 4 * jp);
        o0 = a0 + bf2f(qu.x & 0xFFFFu) + sb[4 * jp];
        o1 = a1 + bf2f(qu.x >> 16)     + sb[4 * jp + 1];
        o2 = a2 + bf2f(qu.y & 0xFFFFu) + sb[4 * jp + 2];
        o3 = a3 + bf2f(qu.y >> 16)     + sb[4 * jp + 3];
    }
    float m = fmaxf(fmaxf(o0, o1), fmaxf(o2, o3));
    m = fmaxf(m, __shfl_xor(m, 1, 4));
    m = fmaxf(m, __shfl_xor(m, 2, 4));
    float s = __expf(o0 - m) + __expf(o1 - m) + __expf(o2 - m) + __expf(o3 - m);
    s += __shfl_xor(s, 1, 4);
    s += __shfl_xor(s, 2, 4);
    const float l = m + __logf(s);
    if (gn < N) {
        if (bf) {
            uint2 ov; ov.x = pack2(o0 - l, o1 - l); ov.y = pack2(o2 - l, o3 - l);
            ((uint2*)out)[(size_t)gn * 4 + jp] = ov;
        } else {
            ((float4*)out)[(size_t)gn * 4 + jp] =
                make_float4(o0 - l, o1 - l, o2 - l, o3 - l);
        }
    }
}

extern "C" void kernel_launch(void* const* d_in, const int* in_sizes, int n_in,
                              void* d_out, int out_size, void* d_ws, size_t ws_size,
                              hipStream_t stream) {
    const void* x       = d_in[0];
    const int*  ei      = (const int*)d_in[1];
    const void* w1_rel  = d_in[2];
    const void* w1_root = d_in[3];
    const void* b1      = d_in[4];
    const void* w2_rel  = d_in[5];
    const void* w2_root = d_in[6];
    const void* b2      = d_in[7];

    const int N = in_sizes[0] / DFEAT;                       // 100000
    const int E = in_sizes[1] / 2;                           // 1600000
    const int nbkt = (N + BKT_NODES - 1) / BKT_NODES;        // 782

    unsigned short* p1b = (unsigned short*)d_ws;
    unsigned short* q1b = p1b + (size_t)N * HID;
    unsigned short* p2b = q1b + (size_t)N * HID;
    unsigned short* q2b = p2b + (size_t)N * HID;
    unsigned* eb   = (unsigned*)(q2b + (size_t)N * HID);     // nbkt*CAP u32
    unsigned* csr  = eb + (size_t)nbkt * CAP;                // nbkt*CAP u32
    int* offsets   = (int*)(csr + (size_t)nbkt * CAP);       // N
    int* gcur      = offsets + N;                            // nbkt
    int* flags     = gcur + nbkt;                            // 2

    const int nPart = (E + CHUNK - 1) / CHUNK;               // 196
    const int nLin  = (N + 127) / 128;                       // 782

    k_detect<<<1, 512, 0, stream>>>((const unsigned short*)x, ei, flags, gcur, nbkt);
    k_pl<<<nPart + nLin, 512, 0, stream>>>(ei, eb, gcur, x, w1_rel, w1_root,
                                           p1b, q1b, flags, E, nbkt, N, nPart);
    k_sagg1<<<nbkt, 512, 0, stream>>>(eb, gcur, p1b, q1b, b1, w2_rel, w2_root,
                                      p2b, q2b, csr, offsets, flags, N);
    k_agg2<<<nbkt, 512, 0, stream>>>(offsets, gcur, csr, p2b, q2b, b2,
                                     d_out, flags, N);
}